// Round 1
// baseline (4587.248 us; speedup 1.0000x reference)
//
#include <hip/hip_runtime.h>
#include <hip/hip_bf16.h>
#include <math.h>

// Problem constants
#define Bn 4
#define Sn 1024
#define Dn 2048
#define Hn 16
#define DHn 128
#define BS (Bn * Sn)       // 4096
#define QKVC (3 * Dn)      // 6144

// ---------------------------------------------------------------------------
// Tiled f32 GEMM: C[M,N] = A[M,K] * B[K,N], row-major, dims multiples of 64/16
// BM=BN=64, BK=16, 256 threads, 4x4 microtile per thread.
// ---------------------------------------------------------------------------
__global__ __launch_bounds__(256) void gemm_f32_kernel(
    const float* __restrict__ A, const float* __restrict__ B,
    float* __restrict__ C, int M, int N, int K) {
  __shared__ float As[16][68];  // [BK][BM+4] transposed A tile (pad keeps 16B align + bank spread)
  __shared__ float Bs[16][64];  // [BK][BN]

  const int t = threadIdx.x;
  const int tx = t & 15;        // 0..15 -> N direction
  const int ty = t >> 4;        // 0..15 -> M direction
  const int bm = blockIdx.y * 64;
  const int bn = blockIdx.x * 64;

  float acc[4][4] = {};

  for (int k0 = 0; k0 < K; k0 += 16) {
    // Load A tile 64x16 (one float4 per thread), store transposed
    {
      const int r = t >> 2;            // 0..63
      const int c4 = (t & 3) << 2;     // 0,4,8,12
      const float4 av = *reinterpret_cast<const float4*>(
          &A[(long)(bm + r) * K + k0 + c4]);
      As[c4 + 0][r] = av.x;
      As[c4 + 1][r] = av.y;
      As[c4 + 2][r] = av.z;
      As[c4 + 3][r] = av.w;
    }
    // Load B tile 16x64 (one float4 per thread), natural layout
    {
      const int r = t >> 4;            // 0..15
      const int c4 = (t & 15) << 2;    // 0..60
      const float4 bv = *reinterpret_cast<const float4*>(
          &B[(long)(k0 + r) * N + bn + c4]);
      *reinterpret_cast<float4*>(&Bs[r][c4]) = bv;
    }
    __syncthreads();

#pragma unroll
    for (int kk = 0; kk < 16; ++kk) {
      const float4 a = *reinterpret_cast<const float4*>(&As[kk][ty << 2]);
      const float4 b = *reinterpret_cast<const float4*>(&Bs[kk][tx << 2]);
      acc[0][0] += a.x * b.x; acc[0][1] += a.x * b.y; acc[0][2] += a.x * b.z; acc[0][3] += a.x * b.w;
      acc[1][0] += a.y * b.x; acc[1][1] += a.y * b.y; acc[1][2] += a.y * b.z; acc[1][3] += a.y * b.w;
      acc[2][0] += a.z * b.x; acc[2][1] += a.z * b.y; acc[2][2] += a.z * b.z; acc[2][3] += a.z * b.w;
      acc[3][0] += a.w * b.x; acc[3][1] += a.w * b.y; acc[3][2] += a.w * b.z; acc[3][3] += a.w * b.w;
    }
    __syncthreads();
  }

#pragma unroll
  for (int i = 0; i < 4; ++i) {
#pragma unroll
    for (int j = 0; j < 4; ++j) {
      C[(long)(bm + (ty << 2) + i) * N + bn + (tx << 2) + j] = acc[i][j];
    }
  }
}

// ---------------------------------------------------------------------------
// RoPE applied in-place to q and k slices of qkv [BS, 6144].
// One thread per (b, s, h, pair). pairs per (b,s,h) = DH/2 = 64.
// rope_matrix: [S, 64, 2, 2] f32 -> per pair a float4 {cos, -sin, sin, cos}
// ---------------------------------------------------------------------------
__global__ __launch_bounds__(256) void rope_kernel(
    float* __restrict__ qkv, const float* __restrict__ rope,
    const int* __restrict__ tpos) {
  const int id = blockIdx.x * 256 + threadIdx.x;   // 0 .. 4194303
  const int i = id & 63;           // pair index
  const int h = (id >> 6) & 15;
  const int s = (id >> 10) & 1023;
  const int b = id >> 20;

  const int pos = tpos[s];
  const float4 pe = *reinterpret_cast<const float4*>(&rope[(long)(pos * 64 + i) * 4]);

  float* qp = qkv + (long)(b * Sn + s) * QKVC + h * DHn + 2 * i;
  const float2 q = *reinterpret_cast<const float2*>(qp);
  qp[0] = pe.x * q.x + pe.y * q.y;
  qp[1] = pe.z * q.x + pe.w * q.y;

  float* kp = qp + Dn;
  const float2 k = *reinterpret_cast<const float2*>(kp);
  kp[0] = pe.x * k.x + pe.y * k.y;
  kp[1] = pe.z * k.x + pe.w * k.y;
}

// ---------------------------------------------------------------------------
// Causal attention, one wave (64 lanes) per (b, h, q) row. Online softmax.
// qkv: [BS, 6144] (q | k | v). ctx out: [BS, 2048] in (b, s, h*DH+d) layout.
// ---------------------------------------------------------------------------
__global__ __launch_bounds__(256) void attn_kernel(
    const float* __restrict__ qkv, float* __restrict__ ctx) {
  const int wid = (blockIdx.x << 2) + (threadIdx.x >> 6);  // global wave id
  const int lane = threadIdx.x & 63;
  const int q = wid & 1023;
  const int h = (wid >> 10) & 15;
  const int b = wid >> 14;

  const float* base = qkv + (long)b * Sn * QKVC;
  const float* qp = base + (long)q * QKVC + h * DHn;

  float2 qv = *reinterpret_cast<const float2*>(qp + 2 * lane);
  const float scale = 0.08838834764831845f;  // 1/sqrt(128)
  qv.x *= scale;
  qv.y *= scale;

  float m = -INFINITY, l = 0.f, a0 = 0.f, a1 = 0.f;
  const float* kp = base + Dn + h * DHn + 2 * lane;
  const float* vp = base + 2 * Dn + h * DHn + 2 * lane;

  for (int k = 0; k <= q; ++k) {
    const float2 kv = *reinterpret_cast<const float2*>(kp + (long)k * QKVC);
    float s = qv.x * kv.x + qv.y * kv.y;
#pragma unroll
    for (int off = 32; off; off >>= 1) s += __shfl_xor(s, off);

    const float mn = fmaxf(m, s);
    const float p = __expf(s - mn);
    const float corr = __expf(m - mn);  // exp(-inf)=0 handles first iter
    const float2 vv = *reinterpret_cast<const float2*>(vp + (long)k * QKVC);
    l = l * corr + p;
    a0 = a0 * corr + p * vv.x;
    a1 = a1 * corr + p * vv.y;
    m = mn;
  }

  const float inv = 1.0f / l;
  float* op = ctx + (long)(b * Sn + q) * Dn + h * DHn + 2 * lane;
  op[0] = a0 * inv;
  op[1] = a1 * inv;
}

// ---------------------------------------------------------------------------
extern "C" void kernel_launch(void* const* d_in, const int* in_sizes, int n_in,
                              void* d_out, int out_size, void* d_ws, size_t ws_size,
                              hipStream_t stream) {
  const float* x     = (const float*)d_in[0];   // [B,S,D] f32
  const float* w_qkv = (const float*)d_in[1];   // [D,3D] f32
  const float* w_out = (const float*)d_in[2];   // [D,D] f32
  const float* rope  = (const float*)d_in[3];   // [S,64,2,2] f32
  const int*   tpos  = (const int*)d_in[4];     // [S] i32
  float* out = (float*)d_out;                   // [B,S,D] f32

  float* qkv = (float*)d_ws;                    // BS*6144 f32 = 100.7 MB
  float* ctx = qkv + (size_t)BS * QKVC;         // BS*2048 f32 = 33.6 MB

  // 1) qkv = x @ w_qkv   [4096,2048]x[2048,6144]
  {
    dim3 grid(QKVC / 64, BS / 64);
    gemm_f32_kernel<<<grid, 256, 0, stream>>>(x, w_qkv, qkv, BS, QKVC, Dn);
  }
  // 2) RoPE in-place on q,k
  {
    const int total = Bn * Sn * Hn * (DHn / 2);  // 4194304
    rope_kernel<<<total / 256, 256, 0, stream>>>(qkv, rope, tpos);
  }
  // 3) causal attention -> ctx [4096, 2048]
  {
    const int waves = Bn * Hn * Sn;              // 65536
    attn_kernel<<<waves / 4, 256, 0, stream>>>(qkv, ctx);
  }
  // 4) out = ctx @ w_out  [4096,2048]x[2048,2048]
  {
    dim3 grid(Dn / 64, BS / 64);
    gemm_f32_kernel<<<grid, 256, 0, stream>>>(ctx, w_out, out, BS, Dn, Dn);
  }
}

// Round 2
// 324.641 us; speedup vs baseline: 14.1302x; 14.1302x over previous
//
#include <hip/hip_runtime.h>
#include <hip/hip_bf16.h>
#include <math.h>

#define Bn 4
#define Sn 1024
#define Dn 2048
#define Hn 16
#define DHn 128
#define BS (Bn * Sn)       // 4096
#define QKVC (3 * Dn)      // 6144

typedef __attribute__((ext_vector_type(8))) short short8;   // 8 x bf16
typedef __attribute__((ext_vector_type(4))) float float4v;  // MFMA acc

// f32 -> bf16 (round-to-nearest-even)
__device__ inline unsigned short f2bf(float x) {
  union { float f; unsigned int u; } v; v.f = x;
  unsigned int r = v.u + 0x7fffu + ((v.u >> 16) & 1u);
  return (unsigned short)(r >> 16);
}
__device__ inline float bf2f(unsigned short b) {
  union { unsigned int u; float f; } v; v.u = ((unsigned int)b) << 16;
  return v.f;
}

// ---------------------------------------------------------------------------
// x f32 -> bf16, 8 elems/thread
// ---------------------------------------------------------------------------
__global__ __launch_bounds__(256) void cvt_f32_bf16(
    const float* __restrict__ in, unsigned short* __restrict__ out, int n8) {
  int id = blockIdx.x * 256 + threadIdx.x;
  if (id >= n8) return;
  const float4* p = reinterpret_cast<const float4*>(in) + 2 * (size_t)id;
  float4 a = p[0], b = p[1];
  short8 o;
  o[0] = (short)f2bf(a.x); o[1] = (short)f2bf(a.y);
  o[2] = (short)f2bf(a.z); o[3] = (short)f2bf(a.w);
  o[4] = (short)f2bf(b.x); o[5] = (short)f2bf(b.y);
  o[6] = (short)f2bf(b.z); o[7] = (short)f2bf(b.w);
  *reinterpret_cast<short8*>(out + 8 * (size_t)id) = o;
}

// ---------------------------------------------------------------------------
// Weight transpose+convert: w [K][N] f32 -> wT [N][K] bf16. 64x64 tiles.
// ---------------------------------------------------------------------------
__global__ __launch_bounds__(256) void transpose_cvt(
    const float* __restrict__ w, unsigned short* __restrict__ wT, int K, int N) {
  __shared__ unsigned short t[64][72];
  const int c0 = blockIdx.x * 64;  // N
  const int r0 = blockIdx.y * 64;  // K
  const int tid = threadIdx.x;
  const int r = tid >> 2;
  const int cb = (tid & 3) * 16;
#pragma unroll
  for (int it = 0; it < 4; ++it) {
    float4 v = *reinterpret_cast<const float4*>(&w[(long)(r0 + r) * N + c0 + cb + 4 * it]);
    t[r][cb + 4 * it + 0] = f2bf(v.x);
    t[r][cb + 4 * it + 1] = f2bf(v.y);
    t[r][cb + 4 * it + 2] = f2bf(v.z);
    t[r][cb + 4 * it + 3] = f2bf(v.w);
  }
  __syncthreads();
  // write wT[c0+r][r0+cb .. +15] = t[cb+e][r]
  unsigned short o[16];
#pragma unroll
  for (int e = 0; e < 16; ++e) o[e] = t[cb + e][r];
  unsigned short* dst = &wT[(long)(c0 + r) * K + r0 + cb];
  *reinterpret_cast<short8*>(dst) = *reinterpret_cast<short8*>(&o[0]);
  *reinterpret_cast<short8*>(dst + 8) = *reinterpret_cast<short8*>(&o[8]);
}

// ---------------------------------------------------------------------------
// bf16 MFMA GEMM: C[M,N] = A[M,K] * BT[N,K]^T.  128x128 tile, BK=32,
// 256 thr = 4 waves (2x2), each wave 64x64 = 4x4 frags of 16x16x32.
// ---------------------------------------------------------------------------
template <bool OUT_BF16>
__global__ __launch_bounds__(256) void gemm_bf16(
    const unsigned short* __restrict__ A, const unsigned short* __restrict__ BT,
    void* __restrict__ Cout, int M, int N, int K) {
  __shared__ unsigned short As[128][40];
  __shared__ unsigned short Bs[128][40];
  const int tid = threadIdx.x;
  const int wid = tid >> 6, lane = tid & 63;
  const int c = lane & 15, g = lane >> 4;
  const int wr = wid >> 1, wc = wid & 1;
  const int m0 = blockIdx.y * 128, n0 = blockIdx.x * 128;

  float4v acc[4][4];
#pragma unroll
  for (int i = 0; i < 4; ++i)
#pragma unroll
    for (int j = 0; j < 4; ++j) acc[i][j] = (float4v){0.f, 0.f, 0.f, 0.f};

  const int srow = tid >> 1, shalf = tid & 1;
  const unsigned short* aptr = A + (long)(m0 + srow) * K + shalf * 16;
  const unsigned short* bptr = BT + (long)(n0 + srow) * K + shalf * 16;

  for (int k0 = 0; k0 < K; k0 += 32) {
    short8 a0 = *reinterpret_cast<const short8*>(aptr);
    short8 a1 = *reinterpret_cast<const short8*>(aptr + 8);
    short8 b0 = *reinterpret_cast<const short8*>(bptr);
    short8 b1 = *reinterpret_cast<const short8*>(bptr + 8);
    aptr += 32; bptr += 32;
    *reinterpret_cast<short8*>(&As[srow][shalf * 16]) = a0;
    *reinterpret_cast<short8*>(&As[srow][shalf * 16 + 8]) = a1;
    *reinterpret_cast<short8*>(&Bs[srow][shalf * 16]) = b0;
    *reinterpret_cast<short8*>(&Bs[srow][shalf * 16 + 8]) = b1;
    __syncthreads();

    short8 af[4], bfr[4];
#pragma unroll
    for (int mi = 0; mi < 4; ++mi)
      af[mi] = *reinterpret_cast<const short8*>(&As[wr * 64 + mi * 16 + c][g * 8]);
#pragma unroll
    for (int ni = 0; ni < 4; ++ni)
      bfr[ni] = *reinterpret_cast<const short8*>(&Bs[wc * 64 + ni * 16 + c][g * 8]);
#pragma unroll
    for (int mi = 0; mi < 4; ++mi)
#pragma unroll
      for (int ni = 0; ni < 4; ++ni)
        acc[mi][ni] = __builtin_amdgcn_mfma_f32_16x16x32_bf16(
            af[mi], bfr[ni], acc[mi][ni], 0, 0, 0);
    __syncthreads();
  }

#pragma unroll
  for (int mi = 0; mi < 4; ++mi)
#pragma unroll
    for (int ni = 0; ni < 4; ++ni)
#pragma unroll
      for (int j = 0; j < 4; ++j) {
        const int m = m0 + wr * 64 + mi * 16 + g * 4 + j;
        const int n = n0 + wc * 64 + ni * 16 + c;
        if (OUT_BF16)
          ((unsigned short*)Cout)[(long)m * N + n] = f2bf(acc[mi][ni][j]);
        else
          ((float*)Cout)[(long)m * N + n] = acc[mi][ni][j];
      }
}

// ---------------------------------------------------------------------------
// RoPE in-place on bf16 qkv; q additionally scaled by 1/sqrt(DH).
// ---------------------------------------------------------------------------
__global__ __launch_bounds__(256) void rope_bf16(
    unsigned short* __restrict__ qkv, const float* __restrict__ rope,
    const int* __restrict__ tpos) {
  const int id = blockIdx.x * 256 + threadIdx.x;  // 4M
  const int i = id & 63;
  const int h = (id >> 6) & 15;
  const int s = (id >> 10) & 1023;
  const int b = id >> 20;
  const int pos = tpos[s];
  const float4 pe = *reinterpret_cast<const float4*>(&rope[(long)(pos * 64 + i) * 4]);

  unsigned short* qp = qkv + (long)(b * Sn + s) * QKVC + h * DHn + 2 * i;
  const float sc = 0.08838834764831845f;  // 1/sqrt(128)
  float qx = bf2f(qp[0]), qy = bf2f(qp[1]);
  qp[0] = f2bf((pe.x * qx + pe.y * qy) * sc);
  qp[1] = f2bf((pe.z * qx + pe.w * qy) * sc);

  unsigned short* kp = qp + Dn;
  float kx = bf2f(kp[0]), ky = bf2f(kp[1]);
  kp[0] = f2bf(pe.x * kx + pe.y * ky);
  kp[1] = f2bf(pe.z * kx + pe.w * ky);
}

// ---------------------------------------------------------------------------
// V transpose: qkv v-slice [b,s,h*128+d] -> vT [(b*16+h)*128+d][s]
// ---------------------------------------------------------------------------
__global__ __launch_bounds__(256) void transpose_v(
    const unsigned short* __restrict__ qkv, unsigned short* __restrict__ vT) {
  __shared__ unsigned short t[64][136];  // [s-local][d], pad 8
  const int s0 = blockIdx.x * 64;
  const int h = blockIdx.y;
  const int b = blockIdx.z;
  const int tid = threadIdx.x;
  const int r = tid >> 2, cb = (tid & 3) * 32;
  const unsigned short* src = qkv + (long)(b * Sn + s0 + r) * QKVC + 2 * Dn + h * DHn + cb;
#pragma unroll
  for (int it = 0; it < 4; ++it)
    *reinterpret_cast<short8*>(&t[r][cb + 8 * it]) =
        *reinterpret_cast<const short8*>(src + 8 * it);
  __syncthreads();
  const int d = tid >> 1, sb = (tid & 1) * 32;
  unsigned short* dst = vT + ((long)(b * Hn + h) * DHn + d) * Sn + s0 + sb;
#pragma unroll
  for (int it = 0; it < 4; ++it) {
    unsigned short o[8];
#pragma unroll
    for (int e = 0; e < 8; ++e) o[e] = t[sb + 8 * it + e][d];
    *reinterpret_cast<short8*>(dst + 8 * it) = *reinterpret_cast<short8*>(&o[0]);
  }
}

// ---------------------------------------------------------------------------
// Flash attention (bf16 MFMA). Block: 256 thr = 4 waves; (b,h,qt) per block.
// Each wave: 16 q rows. S^T = K*Q^T (swapped) so softmax is lane-local per q.
// PV: O^T = V^T * P^T.  Online softmax in f32.
// ---------------------------------------------------------------------------
__global__ __launch_bounds__(256) void attn_mfma(
    const unsigned short* __restrict__ qkv, const unsigned short* __restrict__ vT,
    unsigned short* __restrict__ ctx) {
  __shared__ unsigned short Ks[64][136];    // [kv][d] pad 8
  __shared__ unsigned short Vs[128][72];    // [d][kv] pad 8
  __shared__ unsigned short Ps[4][16][72];  // per-wave [q][kv] pad 8
  const int qt = blockIdx.x, h = blockIdx.y, b = blockIdx.z;
  const int tid = threadIdx.x, w = tid >> 6, lane = tid & 63;
  const int c = lane & 15, g = lane >> 4;
  const long qkvbase = (long)b * Sn * QKVC;

  // Q fragments (B-operand of S^T): lane reads Q[q=qt*64+16w+c][kc*32+8g .. +7]
  short8 qf[4];
  {
    const unsigned short* qrow =
        qkv + qkvbase + (long)(qt * 64 + w * 16 + c) * QKVC + h * DHn;
#pragma unroll
    for (int kc = 0; kc < 4; ++kc)
      qf[kc] = *reinterpret_cast<const short8*>(qrow + kc * 32 + g * 8);
  }

  float m = -INFINITY, lsum = 0.f;
  float4v ot[8];
#pragma unroll
  for (int fd = 0; fd < 8; ++fd) ot[fd] = (float4v){0.f, 0.f, 0.f, 0.f};

  const int sr = tid >> 2, scb = tid & 3;        // K staging
  const int vr = tid >> 1, vsb = (tid & 1) * 32; // V staging
  const unsigned short* kbase = qkv + qkvbase + Dn + h * DHn;
  const unsigned short* vbase = vT + (long)(b * Hn + h) * DHn * Sn;

  for (int kt = 0; kt <= qt; ++kt) {
    __syncthreads();  // all waves done reading previous tile
    // stage K tile [64][128]
#pragma unroll
    for (int it = 0; it < 4; ++it) {
      const int ch = scb + 4 * it;
      short8 kv8 = *reinterpret_cast<const short8*>(
          kbase + (long)(kt * 64 + sr) * QKVC + ch * 8);
      *reinterpret_cast<short8*>(&Ks[sr][ch * 8]) = kv8;
    }
    // stage V^T tile [128][64]
#pragma unroll
    for (int it = 0; it < 4; ++it) {
      const int cs = vsb + 8 * it;
      short8 vv = *reinterpret_cast<const short8*>(
          vbase + (long)vr * Sn + kt * 64 + cs);
      *reinterpret_cast<short8*>(&Vs[vr][cs]) = vv;
    }
    __syncthreads();

    // S^T frags: rows kv (4 frags of 16), cols q (16)
    float4v sc[4];
#pragma unroll
    for (int f = 0; f < 4; ++f) sc[f] = (float4v){0.f, 0.f, 0.f, 0.f};
#pragma unroll
    for (int f = 0; f < 4; ++f)
#pragma unroll
      for (int kc = 0; kc < 4; ++kc) {
        short8 kf = *reinterpret_cast<const short8*>(&Ks[f * 16 + c][kc * 32 + g * 8]);
        sc[f] = __builtin_amdgcn_mfma_f32_16x16x32_bf16(kf, qf[kc], sc[f], 0, 0, 0);
      }

    // causal mask on diagonal tile: kv_local > q_local -> -inf
    if (kt == qt) {
      const int qloc = w * 16 + c;
#pragma unroll
      for (int f = 0; f < 4; ++f)
#pragma unroll
        for (int j = 0; j < 4; ++j)
          if (f * 16 + g * 4 + j > qloc) sc[f][j] = -INFINITY;
    }

    // online softmax (state per q = lane col c, replicated across g)
    float tmax = -INFINITY;
#pragma unroll
    for (int f = 0; f < 4; ++f)
#pragma unroll
      for (int j = 0; j < 4; ++j) tmax = fmaxf(tmax, sc[f][j]);
    tmax = fmaxf(tmax, __shfl_xor(tmax, 16));
    tmax = fmaxf(tmax, __shfl_xor(tmax, 32));
    const float mnew = fmaxf(m, tmax);
    const float corr = __expf(m - mnew);
    float psum = 0.f;
#pragma unroll
    for (int f = 0; f < 4; ++f)
#pragma unroll
      for (int j = 0; j < 4; ++j) {
        sc[f][j] = __expf(sc[f][j] - mnew);
        psum += sc[f][j];
      }
    psum += __shfl_xor(psum, 16);
    psum += __shfl_xor(psum, 32);
    lsum = lsum * corr + psum;
    m = mnew;
#pragma unroll
    for (int fd = 0; fd < 8; ++fd) ot[fd] *= corr;

    // P -> bf16 LDS: Ps[w][q=c][kv = f*16 + g*4 + j]
#pragma unroll
    for (int f = 0; f < 4; ++f) {
      unsigned int lo = (unsigned)f2bf(sc[f][0]) | ((unsigned)f2bf(sc[f][1]) << 16);
      unsigned int hi = (unsigned)f2bf(sc[f][2]) | ((unsigned)f2bf(sc[f][3]) << 16);
      uint2 pk; pk.x = lo; pk.y = hi;
      *reinterpret_cast<uint2*>(&Ps[w][c][f * 16 + g * 4]) = pk;
    }

    // PV: O^T += V^T * P^T
    short8 pf0 = *reinterpret_cast<const short8*>(&Ps[w][c][g * 8]);
    short8 pf1 = *reinterpret_cast<const short8*>(&Ps[w][c][32 + g * 8]);
#pragma unroll
    for (int fd = 0; fd < 8; ++fd) {
      short8 vf0 = *reinterpret_cast<const short8*>(&Vs[fd * 16 + c][g * 8]);
      short8 vf1 = *reinterpret_cast<const short8*>(&Vs[fd * 16 + c][32 + g * 8]);
      ot[fd] = __builtin_amdgcn_mfma_f32_16x16x32_bf16(vf0, pf0, ot[fd], 0, 0, 0);
      ot[fd] = __builtin_amdgcn_mfma_f32_16x16x32_bf16(vf1, pf1, ot[fd], 0, 0, 0);
    }
  }

  // epilogue: ctx[b][q][h*128 + d] = O^T[d][q] / lsum   (bf16)
  const float inv = 1.0f / lsum;
  unsigned short* orow = ctx + (long)(b * Sn + qt * 64 + w * 16 + c) * Dn + h * DHn;
#pragma unroll
  for (int fd = 0; fd < 8; ++fd) {
    const int d = fd * 16 + g * 4;
    uint2 pk;
    pk.x = (unsigned)f2bf(ot[fd][0] * inv) | ((unsigned)f2bf(ot[fd][1] * inv) << 16);
    pk.y = (unsigned)f2bf(ot[fd][2] * inv) | ((unsigned)f2bf(ot[fd][3] * inv) << 16);
    *reinterpret_cast<uint2*>(orow + d) = pk;
  }
}

// ---------------------------------------------------------------------------
extern "C" void kernel_launch(void* const* d_in, const int* in_sizes, int n_in,
                              void* d_out, int out_size, void* d_ws, size_t ws_size,
                              hipStream_t stream) {
  const float* x     = (const float*)d_in[0];
  const float* w_qkv = (const float*)d_in[1];
  const float* w_out = (const float*)d_in[2];
  const float* rope  = (const float*)d_in[3];
  const int*   tpos  = (const int*)d_in[4];
  float* out = (float*)d_out;

  unsigned short* x16   = (unsigned short*)d_ws;        // 8,388,608
  unsigned short* wqkvT = x16 + (size_t)BS * Dn;        // 12,582,912
  unsigned short* woutT = wqkvT + (size_t)Dn * QKVC;    // 4,194,304
  unsigned short* qkv16 = woutT + (size_t)Dn * Dn;      // 25,165,824
  unsigned short* vT16  = qkv16 + (size_t)BS * QKVC;    // 8,388,608
  unsigned short* ctx16 = vT16 + (size_t)BS * Dn;       // 8,388,608

  // 1) converts / weight transposes
  cvt_f32_bf16<<<(BS * Dn / 8 + 255) / 256, 256, 0, stream>>>(x, x16, BS * Dn / 8);
  {
    dim3 g1(QKVC / 64, Dn / 64);
    transpose_cvt<<<g1, 256, 0, stream>>>(w_qkv, wqkvT, Dn, QKVC);
    dim3 g2(Dn / 64, Dn / 64);
    transpose_cvt<<<g2, 256, 0, stream>>>(w_out, woutT, Dn, Dn);
  }
  // 2) qkv = x16 @ wqkvT^T  -> bf16
  {
    dim3 grid(QKVC / 128, BS / 128);
    gemm_bf16<true><<<grid, 256, 0, stream>>>(x16, wqkvT, qkv16, BS, QKVC, Dn);
  }
  // 3) RoPE (+ q prescale)
  rope_bf16<<<(Bn * Sn * Hn * 64) / 256, 256, 0, stream>>>(qkv16, rope, tpos);
  // 4) V transpose
  {
    dim3 grid(Sn / 64, Hn, Bn);
    transpose_v<<<grid, 256, 0, stream>>>(qkv16, vT16);
  }
  // 5) attention
  {
    dim3 grid(Sn / 64, Hn, Bn);
    attn_mfma<<<grid, 256, 0, stream>>>(qkv16, vT16, ctx16);
  }
  // 6) out = ctx16 @ woutT^T -> f32
  {
    dim3 grid(Dn / 128, BS / 128);
    gemm_bf16<false><<<grid, 256, 0, stream>>>(ctx16, woutT, out, BS, Dn, Dn);
  }
}

// Round 3
// 312.838 us; speedup vs baseline: 14.6633x; 1.0377x over previous
//
#include <hip/hip_runtime.h>
#include <hip/hip_bf16.h>
#include <math.h>

#define Bn 4
#define Sn 1024
#define Dn 2048
#define Hn 16
#define DHn 128
#define BS (Bn * Sn)       // 4096
#define QKVC (3 * Dn)      // 6144

typedef __attribute__((ext_vector_type(8))) short short8;   // 8 x bf16
typedef __attribute__((ext_vector_type(4))) float float4v;  // MFMA acc

// f32 -> bf16 (round-to-nearest-even)
__device__ inline unsigned short f2bf(float x) {
  union { float f; unsigned int u; } v; v.f = x;
  unsigned int r = v.u + 0x7fffu + ((v.u >> 16) & 1u);
  return (unsigned short)(r >> 16);
}
__device__ inline float bf2f(unsigned short b) {
  union { unsigned int u; float f; } v; v.u = ((unsigned int)b) << 16;
  return v.f;
}

// async global->LDS, 16B per lane. LDS dest = wave-uniform base + lane*16.
__device__ __forceinline__ void gload16(const unsigned short* g, unsigned short* l) {
  __builtin_amdgcn_global_load_lds(
      (const __attribute__((address_space(1))) unsigned int*)g,
      (__attribute__((address_space(3))) unsigned int*)l, 16, 0, 0);
}

// ---------------------------------------------------------------------------
// x f32 -> bf16, 8 elems/thread
// ---------------------------------------------------------------------------
__global__ __launch_bounds__(256) void cvt_f32_bf16(
    const float* __restrict__ in, unsigned short* __restrict__ out, int n8) {
  int id = blockIdx.x * 256 + threadIdx.x;
  if (id >= n8) return;
  const float4* p = reinterpret_cast<const float4*>(in) + 2 * (size_t)id;
  float4 a = p[0], b = p[1];
  short8 o;
  o[0] = (short)f2bf(a.x); o[1] = (short)f2bf(a.y);
  o[2] = (short)f2bf(a.z); o[3] = (short)f2bf(a.w);
  o[4] = (short)f2bf(b.x); o[5] = (short)f2bf(b.y);
  o[6] = (short)f2bf(b.z); o[7] = (short)f2bf(b.w);
  *reinterpret_cast<short8*>(out + 8 * (size_t)id) = o;
}

// ---------------------------------------------------------------------------
// Weight transpose+convert: w [K][N] f32 -> wT [N][K] bf16. 64x64 tiles.
// ---------------------------------------------------------------------------
__global__ __launch_bounds__(256) void transpose_cvt(
    const float* __restrict__ w, unsigned short* __restrict__ wT, int K, int N) {
  __shared__ unsigned short t[64][72];
  const int c0 = blockIdx.x * 64;  // N
  const int r0 = blockIdx.y * 64;  // K
  const int tid = threadIdx.x;
  const int r = tid >> 2;
  const int cb = (tid & 3) * 16;
#pragma unroll
  for (int it = 0; it < 4; ++it) {
    float4 v = *reinterpret_cast<const float4*>(&w[(long)(r0 + r) * N + c0 + cb + 4 * it]);
    t[r][cb + 4 * it + 0] = f2bf(v.x);
    t[r][cb + 4 * it + 1] = f2bf(v.y);
    t[r][cb + 4 * it + 2] = f2bf(v.z);
    t[r][cb + 4 * it + 3] = f2bf(v.w);
  }
  __syncthreads();
  unsigned short o[16];
#pragma unroll
  for (int e = 0; e < 16; ++e) o[e] = t[cb + e][r];
  unsigned short* dst = &wT[(long)(c0 + r) * K + r0 + cb];
  *reinterpret_cast<short8*>(dst) = *reinterpret_cast<short8*>(&o[0]);
  *reinterpret_cast<short8*>(dst + 8) = *reinterpret_cast<short8*>(&o[8]);
}

// ---------------------------------------------------------------------------
// bf16 MFMA GEMM (m97 structure): C[M,N] = A[M,K] * BT[N,K]^T.
// 128x128 tile, BK=32, 256 thr = 4 waves (2x2), linear LDS, global_load_lds.
// ---------------------------------------------------------------------------
template <bool OUT_BF16>
__global__ __launch_bounds__(256) void gemm_lds(
    const unsigned short* __restrict__ A, const unsigned short* __restrict__ BT,
    void* __restrict__ Cout, int M, int N, int K) {
  __shared__ unsigned short As[128 * 32];  // linear [128][32], no pad
  __shared__ unsigned short Bs[128 * 32];
  const int tid = threadIdx.x;
  const int wid = tid >> 6, lane = tid & 63;
  const int c = lane & 15, g = lane >> 4;
  const int wr = wid >> 1, wc = wid & 1;
  const int m0 = blockIdx.y * 128, n0 = blockIdx.x * 128;

  float4v acc[4][4];
#pragma unroll
  for (int i = 0; i < 4; ++i)
#pragma unroll
    for (int j = 0; j < 4; ++j) acc[i][j] = (float4v){0.f, 0.f, 0.f, 0.f};

  // staging: thread t covers linear shorts [(i*256+t)*8, +8) of the [128][32]
  // tile = global row i*64 + (t>>2), cols (t&3)*8 .. +7
  const int srow = tid >> 2, scol = (tid & 3) * 8;
  const unsigned short* a0 = A + (long)(m0 + srow) * K + scol;
  const unsigned short* a1 = A + (long)(m0 + 64 + srow) * K + scol;
  const unsigned short* b0 = BT + (long)(n0 + srow) * K + scol;
  const unsigned short* b1 = BT + (long)(n0 + 64 + srow) * K + scol;
  unsigned short* asd0 = As + wid * 512;         // wave-uniform dests
  unsigned short* asd1 = As + 2048 + wid * 512;
  unsigned short* bsd0 = Bs + wid * 512;
  unsigned short* bsd1 = Bs + 2048 + wid * 512;

  for (int k0 = 0; k0 < K; k0 += 32) {
    gload16(a0 + k0, asd0);
    gload16(a1 + k0, asd1);
    gload16(b0 + k0, bsd0);
    gload16(b1 + k0, bsd1);
    __syncthreads();  // compiler drains vmcnt(0) before barrier

    short8 af[4], bfv[4];
#pragma unroll
    for (int mi = 0; mi < 4; ++mi)
      af[mi] = *reinterpret_cast<const short8*>(As + (wr * 64 + mi * 16 + c) * 32 + g * 8);
#pragma unroll
    for (int ni = 0; ni < 4; ++ni)
      bfv[ni] = *reinterpret_cast<const short8*>(Bs + (wc * 64 + ni * 16 + c) * 32 + g * 8);
#pragma unroll
    for (int mi = 0; mi < 4; ++mi)
#pragma unroll
      for (int ni = 0; ni < 4; ++ni)
        acc[mi][ni] = __builtin_amdgcn_mfma_f32_16x16x32_bf16(
            af[mi], bfv[ni], acc[mi][ni], 0, 0, 0);
    __syncthreads();
  }

#pragma unroll
  for (int mi = 0; mi < 4; ++mi)
#pragma unroll
    for (int ni = 0; ni < 4; ++ni)
#pragma unroll
      for (int j = 0; j < 4; ++j) {
        const int m = m0 + wr * 64 + mi * 16 + g * 4 + j;
        const int n = n0 + wc * 64 + ni * 16 + c;
        if (OUT_BF16)
          ((unsigned short*)Cout)[(long)m * N + n] = f2bf(acc[mi][ni][j]);
        else
          ((float*)Cout)[(long)m * N + n] = acc[mi][ni][j];
      }
}

// ---------------------------------------------------------------------------
// RoPE in-place on bf16 qkv; q additionally scaled by 1/sqrt(DH).
// ---------------------------------------------------------------------------
__global__ __launch_bounds__(256) void rope_bf16(
    unsigned short* __restrict__ qkv, const float* __restrict__ rope,
    const int* __restrict__ tpos) {
  const int id = blockIdx.x * 256 + threadIdx.x;  // 4M
  const int i = id & 63;
  const int h = (id >> 6) & 15;
  const int s = (id >> 10) & 1023;
  const int b = id >> 20;
  const int pos = tpos[s];
  const float4 pe = *reinterpret_cast<const float4*>(&rope[(long)(pos * 64 + i) * 4]);

  unsigned short* qp = qkv + (long)(b * Sn + s) * QKVC + h * DHn + 2 * i;
  const float sc = 0.08838834764831845f;  // 1/sqrt(128)
  float qx = bf2f(qp[0]), qy = bf2f(qp[1]);
  qp[0] = f2bf((pe.x * qx + pe.y * qy) * sc);
  qp[1] = f2bf((pe.z * qx + pe.w * qy) * sc);

  unsigned short* kp = qp + Dn;
  float kx = bf2f(kp[0]), ky = bf2f(kp[1]);
  kp[0] = f2bf(pe.x * kx + pe.y * ky);
  kp[1] = f2bf(pe.z * kx + pe.w * ky);
}

// ---------------------------------------------------------------------------
// V transpose: qkv v-slice [b,s,h*128+d] -> vT [(b*16+h)*128+d][s]
// ---------------------------------------------------------------------------
__global__ __launch_bounds__(256) void transpose_v(
    const unsigned short* __restrict__ qkv, unsigned short* __restrict__ vT) {
  __shared__ unsigned short t[64][136];
  const int s0 = blockIdx.x * 64;
  const int h = blockIdx.y;
  const int b = blockIdx.z;
  const int tid = threadIdx.x;
  const int r = tid >> 2, cb = (tid & 3) * 32;
  const unsigned short* src = qkv + (long)(b * Sn + s0 + r) * QKVC + 2 * Dn + h * DHn + cb;
#pragma unroll
  for (int it = 0; it < 4; ++it)
    *reinterpret_cast<short8*>(&t[r][cb + 8 * it]) =
        *reinterpret_cast<const short8*>(src + 8 * it);
  __syncthreads();
  const int d = tid >> 1, sb = (tid & 1) * 32;
  unsigned short* dst = vT + ((long)(b * Hn + h) * DHn + d) * Sn + s0 + sb;
#pragma unroll
  for (int it = 0; it < 4; ++it) {
    unsigned short o[8];
#pragma unroll
    for (int e = 0; e < 8; ++e) o[e] = t[sb + 8 * it + e][d];
    *reinterpret_cast<short8*>(dst + 8 * it) = *reinterpret_cast<short8*>(&o[0]);
  }
}

// ---------------------------------------------------------------------------
// Flash attention (bf16 MFMA). Block: 256 thr = 4 waves; (b,h,qt) per block.
// S^T = K*Q^T (swapped) so softmax is lane-local per q. PV: O^T = V^T * P^T.
// ---------------------------------------------------------------------------
__global__ __launch_bounds__(256) void attn_mfma(
    const unsigned short* __restrict__ qkv, const unsigned short* __restrict__ vT,
    unsigned short* __restrict__ ctx) {
  __shared__ unsigned short Ks[64][136];
  __shared__ unsigned short Vs[128][72];
  __shared__ unsigned short Ps[4][16][72];
  const int qt = blockIdx.x, h = blockIdx.y, b = blockIdx.z;
  const int tid = threadIdx.x, w = tid >> 6, lane = tid & 63;
  const int c = lane & 15, g = lane >> 4;
  const long qkvbase = (long)b * Sn * QKVC;

  short8 qf[4];
  {
    const unsigned short* qrow =
        qkv + qkvbase + (long)(qt * 64 + w * 16 + c) * QKVC + h * DHn;
#pragma unroll
    for (int kc = 0; kc < 4; ++kc)
      qf[kc] = *reinterpret_cast<const short8*>(qrow + kc * 32 + g * 8);
  }

  float m = -INFINITY, lsum = 0.f;
  float4v ot[8];
#pragma unroll
  for (int fd = 0; fd < 8; ++fd) ot[fd] = (float4v){0.f, 0.f, 0.f, 0.f};

  const int sr = tid >> 2, scb = tid & 3;
  const int vr = tid >> 1, vsb = (tid & 1) * 32;
  const unsigned short* kbase = qkv + qkvbase + Dn + h * DHn;
  const unsigned short* vbase = vT + (long)(b * Hn + h) * DHn * Sn;

  for (int kt = 0; kt <= qt; ++kt) {
    __syncthreads();
#pragma unroll
    for (int it = 0; it < 4; ++it) {
      const int ch = scb + 4 * it;
      short8 kv8 = *reinterpret_cast<const short8*>(
          kbase + (long)(kt * 64 + sr) * QKVC + ch * 8);
      *reinterpret_cast<short8*>(&Ks[sr][ch * 8]) = kv8;
    }
#pragma unroll
    for (int it = 0; it < 4; ++it) {
      const int cs = vsb + 8 * it;
      short8 vv = *reinterpret_cast<const short8*>(
          vbase + (long)vr * Sn + kt * 64 + cs);
      *reinterpret_cast<short8*>(&Vs[vr][cs]) = vv;
    }
    __syncthreads();

    float4v sc[4];
#pragma unroll
    for (int f = 0; f < 4; ++f) sc[f] = (float4v){0.f, 0.f, 0.f, 0.f};
#pragma unroll
    for (int f = 0; f < 4; ++f)
#pragma unroll
      for (int kc = 0; kc < 4; ++kc) {
        short8 kf = *reinterpret_cast<const short8*>(&Ks[f * 16 + c][kc * 32 + g * 8]);
        sc[f] = __builtin_amdgcn_mfma_f32_16x16x32_bf16(kf, qf[kc], sc[f], 0, 0, 0);
      }

    if (kt == qt) {
      const int qloc = w * 16 + c;
#pragma unroll
      for (int f = 0; f < 4; ++f)
#pragma unroll
        for (int j = 0; j < 4; ++j)
          if (f * 16 + g * 4 + j > qloc) sc[f][j] = -INFINITY;
    }

    float tmax = -INFINITY;
#pragma unroll
    for (int f = 0; f < 4; ++f)
#pragma unroll
      for (int j = 0; j < 4; ++j) tmax = fmaxf(tmax, sc[f][j]);
    tmax = fmaxf(tmax, __shfl_xor(tmax, 16));
    tmax = fmaxf(tmax, __shfl_xor(tmax, 32));
    const float mnew = fmaxf(m, tmax);
    const float corr = __expf(m - mnew);
    float psum = 0.f;
#pragma unroll
    for (int f = 0; f < 4; ++f)
#pragma unroll
      for (int j = 0; j < 4; ++j) {
        sc[f][j] = __expf(sc[f][j] - mnew);
        psum += sc[f][j];
      }
    psum += __shfl_xor(psum, 16);
    psum += __shfl_xor(psum, 32);
    lsum = lsum * corr + psum;
    m = mnew;
#pragma unroll
    for (int fd = 0; fd < 8; ++fd) ot[fd] *= corr;

#pragma unroll
    for (int f = 0; f < 4; ++f) {
      unsigned int lo = (unsigned)f2bf(sc[f][0]) | ((unsigned)f2bf(sc[f][1]) << 16);
      unsigned int hi = (unsigned)f2bf(sc[f][2]) | ((unsigned)f2bf(sc[f][3]) << 16);
      uint2 pk; pk.x = lo; pk.y = hi;
      *reinterpret_cast<uint2*>(&Ps[w][c][f * 16 + g * 4]) = pk;
    }

    short8 pf0 = *reinterpret_cast<const short8*>(&Ps[w][c][g * 8]);
    short8 pf1 = *reinterpret_cast<const short8*>(&Ps[w][c][32 + g * 8]);
#pragma unroll
    for (int fd = 0; fd < 8; ++fd) {
      short8 vf0 = *reinterpret_cast<const short8*>(&Vs[fd * 16 + c][g * 8]);
      short8 vf1 = *reinterpret_cast<const short8*>(&Vs[fd * 16 + c][32 + g * 8]);
      ot[fd] = __builtin_amdgcn_mfma_f32_16x16x32_bf16(vf0, pf0, ot[fd], 0, 0, 0);
      ot[fd] = __builtin_amdgcn_mfma_f32_16x16x32_bf16(vf1, pf1, ot[fd], 0, 0, 0);
    }
  }

  const float inv = 1.0f / lsum;
  unsigned short* orow = ctx + (long)(b * Sn + qt * 64 + w * 16 + c) * Dn + h * DHn;
#pragma unroll
  for (int fd = 0; fd < 8; ++fd) {
    const int d = fd * 16 + g * 4;
    uint2 pk;
    pk.x = (unsigned)f2bf(ot[fd][0] * inv) | ((unsigned)f2bf(ot[fd][1] * inv) << 16);
    pk.y = (unsigned)f2bf(ot[fd][2] * inv) | ((unsigned)f2bf(ot[fd][3] * inv) << 16);
    *reinterpret_cast<uint2*>(orow + d) = pk;
  }
}

// ---------------------------------------------------------------------------
extern "C" void kernel_launch(void* const* d_in, const int* in_sizes, int n_in,
                              void* d_out, int out_size, void* d_ws, size_t ws_size,
                              hipStream_t stream) {
  const float* x     = (const float*)d_in[0];
  const float* w_qkv = (const float*)d_in[1];
  const float* w_out = (const float*)d_in[2];
  const float* rope  = (const float*)d_in[3];
  const int*   tpos  = (const int*)d_in[4];
  float* out = (float*)d_out;

  unsigned short* x16   = (unsigned short*)d_ws;
  unsigned short* wqkvT = x16 + (size_t)BS * Dn;
  unsigned short* woutT = wqkvT + (size_t)Dn * QKVC;
  unsigned short* qkv16 = woutT + (size_t)Dn * Dn;
  unsigned short* vT16  = qkv16 + (size_t)BS * QKVC;
  unsigned short* ctx16 = vT16 + (size_t)BS * Dn;

  cvt_f32_bf16<<<(BS * Dn / 8 + 255) / 256, 256, 0, stream>>>(x, x16, BS * Dn / 8);
  {
    dim3 g1(QKVC / 64, Dn / 64);
    transpose_cvt<<<g1, 256, 0, stream>>>(w_qkv, wqkvT, Dn, QKVC);
    dim3 g2(Dn / 64, Dn / 64);
    transpose_cvt<<<g2, 256, 0, stream>>>(w_out, woutT, Dn, Dn);
  }
  {
    dim3 grid(QKVC / 128, BS / 128);
    gemm_lds<true><<<grid, 256, 0, stream>>>(x16, wqkvT, qkv16, BS, QKVC, Dn);
  }
  rope_bf16<<<(Bn * Sn * Hn * 64) / 256, 256, 0, stream>>>(qkv16, rope, tpos);
  {
    dim3 grid(Sn / 64, Hn, Bn);
    transpose_v<<<grid, 256, 0, stream>>>(qkv16, vT16);
  }
  {
    dim3 grid(Sn / 64, Hn, Bn);
    attn_mfma<<<grid, 256, 0, stream>>>(qkv16, vT16, ctx16);
  }
  {
    dim3 grid(Dn / 128, BS / 128);
    gemm_lds<false><<<grid, 256, 0, stream>>>(ctx16, woutT, out, BS, Dn, Dn);
  }
}

// Round 4
// 283.442 us; speedup vs baseline: 16.1841x; 1.1037x over previous
//
#include <hip/hip_runtime.h>
#include <hip/hip_bf16.h>
#include <math.h>

#define Bn 4
#define Sn 1024
#define Dn 2048
#define Hn 16
#define DHn 128
#define BS (Bn * Sn)       // 4096
#define QKVC (3 * Dn)      // 6144

typedef __attribute__((ext_vector_type(8))) short short8;   // 8 x bf16
typedef __attribute__((ext_vector_type(4))) float float4v;  // MFMA acc

// f32 -> bf16 (round-to-nearest-even)
__device__ inline unsigned short f2bf(float x) {
  union { float f; unsigned int u; } v; v.f = x;
  unsigned int r = v.u + 0x7fffu + ((v.u >> 16) & 1u);
  return (unsigned short)(r >> 16);
}
__device__ inline float bf2f(unsigned short b) {
  union { unsigned int u; float f; } v; v.u = ((unsigned int)b) << 16;
  return v.f;
}

// async global->LDS, 16B per lane. LDS dest = wave-uniform base + lane*16.
__device__ __forceinline__ void gload16(const unsigned short* g, unsigned short* l) {
  __builtin_amdgcn_global_load_lds(
      (const __attribute__((address_space(1))) unsigned int*)g,
      (__attribute__((address_space(3))) unsigned int*)l, 16, 0, 0);
}

// ---------------------------------------------------------------------------
// x f32 -> bf16, 8 elems/thread
// ---------------------------------------------------------------------------
__global__ __launch_bounds__(256) void cvt_f32_bf16(
    const float* __restrict__ in, unsigned short* __restrict__ out, int n8) {
  int id = blockIdx.x * 256 + threadIdx.x;
  if (id >= n8) return;
  const float4* p = reinterpret_cast<const float4*>(in) + 2 * (size_t)id;
  float4 a = p[0], b = p[1];
  short8 o;
  o[0] = (short)f2bf(a.x); o[1] = (short)f2bf(a.y);
  o[2] = (short)f2bf(a.z); o[3] = (short)f2bf(a.w);
  o[4] = (short)f2bf(b.x); o[5] = (short)f2bf(b.y);
  o[6] = (short)f2bf(b.z); o[7] = (short)f2bf(b.w);
  *reinterpret_cast<short8*>(out + 8 * (size_t)id) = o;
}

// ---------------------------------------------------------------------------
// Weight transpose+convert: w [K][N] f32 -> wT [N][K] bf16. 64x64 tiles.
// ---------------------------------------------------------------------------
__global__ __launch_bounds__(256) void transpose_cvt(
    const float* __restrict__ w, unsigned short* __restrict__ wT, int K, int N) {
  __shared__ unsigned short t[64][72];
  const int c0 = blockIdx.x * 64;  // N
  const int r0 = blockIdx.y * 64;  // K
  const int tid = threadIdx.x;
  const int r = tid >> 2;
  const int cb = (tid & 3) * 16;
#pragma unroll
  for (int it = 0; it < 4; ++it) {
    float4 v = *reinterpret_cast<const float4*>(&w[(long)(r0 + r) * N + c0 + cb + 4 * it]);
    t[r][cb + 4 * it + 0] = f2bf(v.x);
    t[r][cb + 4 * it + 1] = f2bf(v.y);
    t[r][cb + 4 * it + 2] = f2bf(v.z);
    t[r][cb + 4 * it + 3] = f2bf(v.w);
  }
  __syncthreads();
  unsigned short o[16];
#pragma unroll
  for (int e = 0; e < 16; ++e) o[e] = t[cb + e][r];
  unsigned short* dst = &wT[(long)(c0 + r) * K + r0 + cb];
  *reinterpret_cast<short8*>(dst) = *reinterpret_cast<short8*>(&o[0]);
  *reinterpret_cast<short8*>(dst + 8) = *reinterpret_cast<short8*>(&o[8]);
}

// ---------------------------------------------------------------------------
// 256x256 8-phase bf16 MFMA GEMM (T2+T3+T4+T5): C = A[M,K] * BT[N,K]^T.
// 512 thr = 8 waves (2M x 4N); BK=64; LDS 128 KiB (2 dbuf x 2 halves each op).
// Swizzle: LDS chunk(16B) (r, w) holds global col-window w ^ (r&7)
// (pre-swizzled global source + linear gload_lds dest + swizzled ds_read).
// vmcnt(4) only at phases 4 and 8 (2 half-tiles stay in flight).
// ---------------------------------------------------------------------------
#define AB(buf, h) ((buf) * 16384 + (h) * 8192)            // shorts
#define BB(buf, h) (32768 + (buf) * 16384 + (h) * 8192)    // shorts

template <bool OUT_BF16>
__global__ __launch_bounds__(512, 2) void gemm8p(
    const unsigned short* __restrict__ A, const unsigned short* __restrict__ BT,
    void* __restrict__ Cout, int M, int N, int K) {
  __shared__ unsigned short lds[65536];  // 128 KiB
  const int tid = threadIdx.x;
  const int wid = tid >> 6, lane = tid & 63;
  const int c = lane & 15, g = lane >> 4;
  const int wr = wid >> 2, wc = wid & 3;
  const int cg7 = c & 7;
  const int brow = (wc & 1) * 64;

  // XCD-aware block swizzle (nwg % 8 == 0 for all our grids)
  const int nwg = gridDim.x * gridDim.y;
  const int bid = blockIdx.y * gridDim.x + blockIdx.x;
  const int swz = (bid & 7) * (nwg >> 3) + (bid >> 3);
  const int m0 = (swz / gridDim.x) * 256, n0 = (swz % gridDim.x) * 256;

  const int nt = K >> 6;        // 64-wide K-tiles (32 for K=2048)
  const int tmask = nt - 1;

  float4v acc[8][4];
#pragma unroll
  for (int i = 0; i < 8; ++i)
#pragma unroll
    for (int j = 0; j < 4; ++j) acc[i][j] = (float4v){0.f, 0.f, 0.f, 0.f};
  short8 bfr[4][2];

  // stage one half-tile (128 rows x 64 k-shorts) with inverse-swizzled source
  auto STAGE = [&](const unsigned short* gbase, int sbase) {
#pragma unroll
    for (int j = 0; j < 2; ++j) {
      const int ch = j * 512 + tid;
      const int r = ch >> 3;
      const int wo = (ch & 7) ^ (r & 7);
      gload16(gbase + (long)r * K + wo * 8, lds + sbase + j * 4096 + wid * 512);
    }
  };

#define PHASE(BUF, Q, STAGE_STMT, DO_VMCNT)                                    \
  {                                                                            \
    __builtin_amdgcn_sched_barrier(0);                                         \
    short8 afr[2][2];                                                          \
    _Pragma("unroll") for (int mi2 = 0; mi2 < 2; ++mi2)                        \
      _Pragma("unroll") for (int ks = 0; ks < 2; ++ks)                         \
        afr[mi2][ks] = *(const short8*)(lds + AB(BUF, 0) + wr * 8192 +         \
            ((Q) * 32 + mi2 * 16 + c) * 64 + (((ks * 4 + g) ^ cg7) << 3));     \
    if ((Q) == 0) {                                                            \
      _Pragma("unroll") for (int ni = 0; ni < 4; ++ni)                         \
        _Pragma("unroll") for (int ks = 0; ks < 2; ++ks)                       \
          bfr[ni][ks] = *(const short8*)(lds + BB(BUF, 0) + (wc >> 1) * 8192 + \
              (brow + ni * 16 + c) * 64 + (((ks * 4 + g) ^ cg7) << 3));        \
    }                                                                          \
    STAGE_STMT;                                                                \
    __builtin_amdgcn_sched_barrier(0);                                         \
    __builtin_amdgcn_s_barrier();                                              \
    asm volatile("s_waitcnt lgkmcnt(0)" ::: "memory");                         \
    __builtin_amdgcn_sched_barrier(0);                                         \
    __builtin_amdgcn_s_setprio(1);                                             \
    _Pragma("unroll") for (int mi2 = 0; mi2 < 2; ++mi2)                        \
      _Pragma("unroll") for (int ni = 0; ni < 4; ++ni)                         \
        _Pragma("unroll") for (int ks = 0; ks < 2; ++ks)                       \
          acc[(Q) * 2 + mi2][ni] = __builtin_amdgcn_mfma_f32_16x16x32_bf16(    \
              afr[mi2][ks], bfr[ni][ks], acc[(Q) * 2 + mi2][ni], 0, 0, 0);     \
    __builtin_amdgcn_s_setprio(0);                                             \
    if (DO_VMCNT) {                                                            \
      asm volatile("s_waitcnt vmcnt(4)" ::: "memory");                         \
      __builtin_amdgcn_sched_barrier(0);                                       \
    }                                                                          \
    __builtin_amdgcn_s_barrier();                                              \
  }

  // Prologue: stage A(0), B(0), B(1); leave B(1) in flight.
  STAGE(A + (long)m0 * K, AB(0, 0));
  STAGE(A + (long)(m0 + 128) * K, AB(0, 1));
  STAGE(BT + (long)n0 * K, BB(0, 0));
  STAGE(BT + (long)(n0 + 128) * K, BB(0, 1));
  STAGE(BT + (long)n0 * K + 64, BB(1, 0));
  STAGE(BT + (long)(n0 + 128) * K + 64, BB(1, 1));
  asm volatile("s_waitcnt vmcnt(4)" ::: "memory");
  __builtin_amdgcn_sched_barrier(0);
  __builtin_amdgcn_s_barrier();

  for (int it2 = 0; it2 < nt / 2; ++it2) {
    const long T1 = (long)(2 * it2 + 1) * 64;
    const long T2 = (long)((2 * it2 + 2) & tmask) * 64;
    const long T3 = (long)((2 * it2 + 3) & tmask) * 64;
    PHASE(0, 0, STAGE(A + (long)m0 * K + T1, AB(1, 0)), false)
    PHASE(0, 1, STAGE(A + (long)(m0 + 128) * K + T1, AB(1, 1)), false)
    PHASE(0, 2, STAGE(BT + (long)n0 * K + T2, BB(0, 0)), false)
    PHASE(0, 3, STAGE(BT + (long)(n0 + 128) * K + T2, BB(0, 1)), true)
    PHASE(1, 0, STAGE(A + (long)m0 * K + T2, AB(0, 0)), false)
    PHASE(1, 1, STAGE(A + (long)(m0 + 128) * K + T2, AB(0, 1)), false)
    PHASE(1, 2, STAGE(BT + (long)n0 * K + T3, BB(1, 0)), false)
    PHASE(1, 3, STAGE(BT + (long)(n0 + 128) * K + T3, BB(1, 1)), true)
  }
#undef PHASE

  // Epilogue
#pragma unroll
  for (int mi = 0; mi < 8; ++mi)
#pragma unroll
    for (int ni = 0; ni < 4; ++ni)
#pragma unroll
      for (int j = 0; j < 4; ++j) {
        const int m = m0 + wr * 128 + mi * 16 + g * 4 + j;
        const int n = n0 + wc * 64 + ni * 16 + c;
        if (OUT_BF16)
          ((unsigned short*)Cout)[(long)m * N + n] = f2bf(acc[mi][ni][j]);
        else
          ((float*)Cout)[(long)m * N + n] = acc[mi][ni][j];
      }
}

// ---------------------------------------------------------------------------
// RoPE in-place on bf16 qkv; q additionally scaled by 1/sqrt(DH).
// ---------------------------------------------------------------------------
__global__ __launch_bounds__(256) void rope_bf16(
    unsigned short* __restrict__ qkv, const float* __restrict__ rope,
    const int* __restrict__ tpos) {
  const int id = blockIdx.x * 256 + threadIdx.x;  // 4M
  const int i = id & 63;
  const int h = (id >> 6) & 15;
  const int s = (id >> 10) & 1023;
  const int b = id >> 20;
  const int pos = tpos[s];
  const float4 pe = *reinterpret_cast<const float4*>(&rope[(long)(pos * 64 + i) * 4]);

  unsigned short* qp = qkv + (long)(b * Sn + s) * QKVC + h * DHn + 2 * i;
  const float sc = 0.08838834764831845f;  // 1/sqrt(128)
  float qx = bf2f(qp[0]), qy = bf2f(qp[1]);
  qp[0] = f2bf((pe.x * qx + pe.y * qy) * sc);
  qp[1] = f2bf((pe.z * qx + pe.w * qy) * sc);

  unsigned short* kp = qp + Dn;
  float kx = bf2f(kp[0]), ky = bf2f(kp[1]);
  kp[0] = f2bf(pe.x * kx + pe.y * ky);
  kp[1] = f2bf(pe.z * kx + pe.w * ky);
}

// ---------------------------------------------------------------------------
// V transpose: qkv v-slice [b,s,h*128+d] -> vT [(b*16+h)*128+d][s]
// ---------------------------------------------------------------------------
__global__ __launch_bounds__(256) void transpose_v(
    const unsigned short* __restrict__ qkv, unsigned short* __restrict__ vT) {
  __shared__ unsigned short t[64][136];
  const int s0 = blockIdx.x * 64;
  const int h = blockIdx.y;
  const int b = blockIdx.z;
  const int tid = threadIdx.x;
  const int r = tid >> 2, cb = (tid & 3) * 32;
  const unsigned short* src = qkv + (long)(b * Sn + s0 + r) * QKVC + 2 * Dn + h * DHn + cb;
#pragma unroll
  for (int it = 0; it < 4; ++it)
    *reinterpret_cast<short8*>(&t[r][cb + 8 * it]) =
        *reinterpret_cast<const short8*>(src + 8 * it);
  __syncthreads();
  const int d = tid >> 1, sb = (tid & 1) * 32;
  unsigned short* dst = vT + ((long)(b * Hn + h) * DHn + d) * Sn + s0 + sb;
#pragma unroll
  for (int it = 0; it < 4; ++it) {
    unsigned short o[8];
#pragma unroll
    for (int e = 0; e < 8; ++e) o[e] = t[sb + 8 * it + e][d];
    *reinterpret_cast<short8*>(dst + 8 * it) = *reinterpret_cast<short8*>(&o[0]);
  }
}

// ---------------------------------------------------------------------------
// Flash attention (bf16 MFMA). Block: 256 thr = 4 waves; (b,h,qt) per block.
// S^T = K*Q^T (swapped) so softmax is lane-local per q. PV: O^T = V^T * P^T.
// ---------------------------------------------------------------------------
__global__ __launch_bounds__(256) void attn_mfma(
    const unsigned short* __restrict__ qkv, const unsigned short* __restrict__ vT,
    unsigned short* __restrict__ ctx) {
  __shared__ unsigned short Ks[64][136];
  __shared__ unsigned short Vs[128][72];
  __shared__ unsigned short Ps[4][16][72];
  const int qt = blockIdx.x, h = blockIdx.y, b = blockIdx.z;
  const int tid = threadIdx.x, w = tid >> 6, lane = tid & 63;
  const int c = lane & 15, g = lane >> 4;
  const long qkvbase = (long)b * Sn * QKVC;

  short8 qf[4];
  {
    const unsigned short* qrow =
        qkv + qkvbase + (long)(qt * 64 + w * 16 + c) * QKVC + h * DHn;
#pragma unroll
    for (int kc = 0; kc < 4; ++kc)
      qf[kc] = *reinterpret_cast<const short8*>(qrow + kc * 32 + g * 8);
  }

  float m = -INFINITY, lsum = 0.f;
  float4v ot[8];
#pragma unroll
  for (int fd = 0; fd < 8; ++fd) ot[fd] = (float4v){0.f, 0.f, 0.f, 0.f};

  const int sr = tid >> 2, scb = tid & 3;
  const int vr = tid >> 1, vsb = (tid & 1) * 32;
  const unsigned short* kbase = qkv + qkvbase + Dn + h * DHn;
  const unsigned short* vbase = vT + (long)(b * Hn + h) * DHn * Sn;

  for (int kt = 0; kt <= qt; ++kt) {
    __syncthreads();
#pragma unroll
    for (int it = 0; it < 4; ++it) {
      const int ch = scb + 4 * it;
      short8 kv8 = *reinterpret_cast<const short8*>(
          kbase + (long)(kt * 64 + sr) * QKVC + ch * 8);
      *reinterpret_cast<short8*>(&Ks[sr][ch * 8]) = kv8;
    }
#pragma unroll
    for (int it = 0; it < 4; ++it) {
      const int cs = vsb + 8 * it;
      short8 vv = *reinterpret_cast<const short8*>(
          vbase + (long)vr * Sn + kt * 64 + cs);
      *reinterpret_cast<short8*>(&Vs[vr][cs]) = vv;
    }
    __syncthreads();

    float4v sc[4];
#pragma unroll
    for (int f = 0; f < 4; ++f) sc[f] = (float4v){0.f, 0.f, 0.f, 0.f};
#pragma unroll
    for (int f = 0; f < 4; ++f)
#pragma unroll
      for (int kc = 0; kc < 4; ++kc) {
        short8 kf = *reinterpret_cast<const short8*>(&Ks[f * 16 + c][kc * 32 + g * 8]);
        sc[f] = __builtin_amdgcn_mfma_f32_16x16x32_bf16(kf, qf[kc], sc[f], 0, 0, 0);
      }

    if (kt == qt) {
      const int qloc = w * 16 + c;
#pragma unroll
      for (int f = 0; f < 4; ++f)
#pragma unroll
        for (int j = 0; j < 4; ++j)
          if (f * 16 + g * 4 + j > qloc) sc[f][j] = -INFINITY;
    }

    float tmax = -INFINITY;
#pragma unroll
    for (int f = 0; f < 4; ++f)
#pragma unroll
      for (int j = 0; j < 4; ++j) tmax = fmaxf(tmax, sc[f][j]);
    tmax = fmaxf(tmax, __shfl_xor(tmax, 16));
    tmax = fmaxf(tmax, __shfl_xor(tmax, 32));
    const float mnew = fmaxf(m, tmax);
    const float corr = __expf(m - mnew);
    float psum = 0.f;
#pragma unroll
    for (int f = 0; f < 4; ++f)
#pragma unroll
      for (int j = 0; j < 4; ++j) {
        sc[f][j] = __expf(sc[f][j] - mnew);
        psum += sc[f][j];
      }
    psum += __shfl_xor(psum, 16);
    psum += __shfl_xor(psum, 32);
    lsum = lsum * corr + psum;
    m = mnew;
#pragma unroll
    for (int fd = 0; fd < 8; ++fd) ot[fd] *= corr;

#pragma unroll
    for (int f = 0; f < 4; ++f) {
      unsigned int lo = (unsigned)f2bf(sc[f][0]) | ((unsigned)f2bf(sc[f][1]) << 16);
      unsigned int hi = (unsigned)f2bf(sc[f][2]) | ((unsigned)f2bf(sc[f][3]) << 16);
      uint2 pk; pk.x = lo; pk.y = hi;
      *reinterpret_cast<uint2*>(&Ps[w][c][f * 16 + g * 4]) = pk;
    }

    short8 pf0 = *reinterpret_cast<const short8*>(&Ps[w][c][g * 8]);
    short8 pf1 = *reinterpret_cast<const short8*>(&Ps[w][c][32 + g * 8]);
#pragma unroll
    for (int fd = 0; fd < 8; ++fd) {
      short8 vf0 = *reinterpret_cast<const short8*>(&Vs[fd * 16 + c][g * 8]);
      short8 vf1 = *reinterpret_cast<const short8*>(&Vs[fd * 16 + c][32 + g * 8]);
      ot[fd] = __builtin_amdgcn_mfma_f32_16x16x32_bf16(vf0, pf0, ot[fd], 0, 0, 0);
      ot[fd] = __builtin_amdgcn_mfma_f32_16x16x32_bf16(vf1, pf1, ot[fd], 0, 0, 0);
    }
  }

  const float inv = 1.0f / lsum;
  unsigned short* orow = ctx + (long)(b * Sn + qt * 64 + w * 16 + c) * Dn + h * DHn;
#pragma unroll
  for (int fd = 0; fd < 8; ++fd) {
    const int d = fd * 16 + g * 4;
    uint2 pk;
    pk.x = (unsigned)f2bf(ot[fd][0] * inv) | ((unsigned)f2bf(ot[fd][1] * inv) << 16);
    pk.y = (unsigned)f2bf(ot[fd][2] * inv) | ((unsigned)f2bf(ot[fd][3] * inv) << 16);
    *reinterpret_cast<uint2*>(orow + d) = pk;
  }
}

// ---------------------------------------------------------------------------
extern "C" void kernel_launch(void* const* d_in, const int* in_sizes, int n_in,
                              void* d_out, int out_size, void* d_ws, size_t ws_size,
                              hipStream_t stream) {
  const float* x     = (const float*)d_in[0];
  const float* w_qkv = (const float*)d_in[1];
  const float* w_out = (const float*)d_in[2];
  const float* rope  = (const float*)d_in[3];
  const int*   tpos  = (const int*)d_in[4];
  float* out = (float*)d_out;

  unsigned short* x16   = (unsigned short*)d_ws;
  unsigned short* wqkvT = x16 + (size_t)BS * Dn;
  unsigned short* woutT = wqkvT + (size_t)Dn * QKVC;
  unsigned short* qkv16 = woutT + (size_t)Dn * Dn;
  unsigned short* vT16  = qkv16 + (size_t)BS * QKVC;
  unsigned short* ctx16 = vT16 + (size_t)BS * Dn;

  cvt_f32_bf16<<<(BS * Dn / 8 + 255) / 256, 256, 0, stream>>>(x, x16, BS * Dn / 8);
  {
    dim3 g1(QKVC / 64, Dn / 64);
    transpose_cvt<<<g1, 256, 0, stream>>>(w_qkv, wqkvT, Dn, QKVC);
    dim3 g2(Dn / 64, Dn / 64);
    transpose_cvt<<<g2, 256, 0, stream>>>(w_out, woutT, Dn, Dn);
  }
  {
    dim3 grid(QKVC / 256, BS / 256);  // 24 x 16 = 384
    gemm8p<true><<<grid, 512, 0, stream>>>(x16, wqkvT, qkv16, BS, QKVC, Dn);
  }
  rope_bf16<<<(Bn * Sn * Hn * 64) / 256, 256, 0, stream>>>(qkv16, rope, tpos);
  {
    dim3 grid(Sn / 64, Hn, Bn);
    transpose_v<<<grid, 256, 0, stream>>>(qkv16, vT16);
  }
  {
    dim3 grid(Sn / 64, Hn, Bn);
    attn_mfma<<<grid, 256, 0, stream>>>(qkv16, vT16, ctx16);
  }
  {
    dim3 grid(Dn / 256, BS / 256);    // 8 x 16 = 128
    gemm8p<false><<<grid, 512, 0, stream>>>(ctx16, woutT, out, BS, Dn, Dn);
  }
}

// Round 5
// 282.746 us; speedup vs baseline: 16.2239x; 1.0025x over previous
//
#include <hip/hip_runtime.h>
#include <hip/hip_bf16.h>
#include <math.h>

#define Bn 4
#define Sn 1024
#define Dn 2048
#define Hn 16
#define DHn 128
#define BS (Bn * Sn)       // 4096
#define QKVC (3 * Dn)      // 6144

typedef __attribute__((ext_vector_type(8))) short short8;   // 8 x bf16
typedef __attribute__((ext_vector_type(4))) float float4v;  // MFMA acc

// f32 -> bf16 (round-to-nearest-even)
__device__ inline unsigned short f2bf(float x) {
  union { float f; unsigned int u; } v; v.f = x;
  unsigned int r = v.u + 0x7fffu + ((v.u >> 16) & 1u);
  return (unsigned short)(r >> 16);
}
__device__ inline float bf2f(unsigned short b) {
  union { unsigned int u; float f; } v; v.u = ((unsigned int)b) << 16;
  return v.f;
}

// async global->LDS, 16B per lane. LDS dest = wave-uniform base + lane*16.
__device__ __forceinline__ void gload16(const unsigned short* g, unsigned short* l) {
  __builtin_amdgcn_global_load_lds(
      (const __attribute__((address_space(1))) unsigned int*)g,
      (__attribute__((address_space(3))) unsigned int*)l, 16, 0, 0);
}

// ---------------------------------------------------------------------------
// x f32 -> bf16, 8 elems/thread
// ---------------------------------------------------------------------------
__global__ __launch_bounds__(256) void cvt_f32_bf16(
    const float* __restrict__ in, unsigned short* __restrict__ out, int n8) {
  int id = blockIdx.x * 256 + threadIdx.x;
  if (id >= n8) return;
  const float4* p = reinterpret_cast<const float4*>(in) + 2 * (size_t)id;
  float4 a = p[0], b = p[1];
  short8 o;
  o[0] = (short)f2bf(a.x); o[1] = (short)f2bf(a.y);
  o[2] = (short)f2bf(a.z); o[3] = (short)f2bf(a.w);
  o[4] = (short)f2bf(b.x); o[5] = (short)f2bf(b.y);
  o[6] = (short)f2bf(b.z); o[7] = (short)f2bf(b.w);
  *reinterpret_cast<short8*>(out + 8 * (size_t)id) = o;
}

// ---------------------------------------------------------------------------
// Weight transpose+convert: w [K][N] f32 -> wT [N][K] bf16. 64x64 tiles.
// ---------------------------------------------------------------------------
__global__ __launch_bounds__(256) void transpose_cvt(
    const float* __restrict__ w, unsigned short* __restrict__ wT, int K, int N) {
  __shared__ unsigned short t[64][72];
  const int c0 = blockIdx.x * 64;  // N
  const int r0 = blockIdx.y * 64;  // K
  const int tid = threadIdx.x;
  const int r = tid >> 2;
  const int cb = (tid & 3) * 16;
#pragma unroll
  for (int it = 0; it < 4; ++it) {
    float4 v = *reinterpret_cast<const float4*>(&w[(long)(r0 + r) * N + c0 + cb + 4 * it]);
    t[r][cb + 4 * it + 0] = f2bf(v.x);
    t[r][cb + 4 * it + 1] = f2bf(v.y);
    t[r][cb + 4 * it + 2] = f2bf(v.z);
    t[r][cb + 4 * it + 3] = f2bf(v.w);
  }
  __syncthreads();
  unsigned short o[16];
#pragma unroll
  for (int e = 0; e < 16; ++e) o[e] = t[cb + e][r];
  unsigned short* dst = &wT[(long)(c0 + r) * K + r0 + cb];
  *reinterpret_cast<short8*>(dst) = *reinterpret_cast<short8*>(&o[0]);
  *reinterpret_cast<short8*>(dst + 8) = *reinterpret_cast<short8*>(&o[8]);
}

// ---------------------------------------------------------------------------
// 256x256 8-phase bf16 MFMA GEMM (T2+T3+T4+T5): C = A[M,K] * BT[N,K]^T.
// ---------------------------------------------------------------------------
#define AB(buf, h) ((buf) * 16384 + (h) * 8192)            // shorts
#define BB(buf, h) (32768 + (buf) * 16384 + (h) * 8192)    // shorts

template <bool OUT_BF16>
__global__ __launch_bounds__(512, 2) void gemm8p(
    const unsigned short* __restrict__ A, const unsigned short* __restrict__ BT,
    void* __restrict__ Cout, int M, int N, int K) {
  __shared__ unsigned short lds[65536];  // 128 KiB
  const int tid = threadIdx.x;
  const int wid = tid >> 6, lane = tid & 63;
  const int c = lane & 15, g = lane >> 4;
  const int wr = wid >> 2, wc = wid & 3;
  const int cg7 = c & 7;
  const int brow = (wc & 1) * 64;

  const int nwg = gridDim.x * gridDim.y;
  const int bid = blockIdx.y * gridDim.x + blockIdx.x;
  const int swz = (bid & 7) * (nwg >> 3) + (bid >> 3);
  const int m0 = (swz / gridDim.x) * 256, n0 = (swz % gridDim.x) * 256;

  const int nt = K >> 6;
  const int tmask = nt - 1;

  float4v acc[8][4];
#pragma unroll
  for (int i = 0; i < 8; ++i)
#pragma unroll
    for (int j = 0; j < 4; ++j) acc[i][j] = (float4v){0.f, 0.f, 0.f, 0.f};
  short8 bfr[4][2];

  auto STAGE = [&](const unsigned short* gbase, int sbase) {
#pragma unroll
    for (int j = 0; j < 2; ++j) {
      const int ch = j * 512 + tid;
      const int r = ch >> 3;
      const int wo = (ch & 7) ^ (r & 7);
      gload16(gbase + (long)r * K + wo * 8, lds + sbase + j * 4096 + wid * 512);
    }
  };

#define PHASE(BUF, Q, STAGE_STMT, DO_VMCNT)                                    \
  {                                                                            \
    __builtin_amdgcn_sched_barrier(0);                                         \
    short8 afr[2][2];                                                          \
    _Pragma("unroll") for (int mi2 = 0; mi2 < 2; ++mi2)                        \
      _Pragma("unroll") for (int ks = 0; ks < 2; ++ks)                         \
        afr[mi2][ks] = *(const short8*)(lds + AB(BUF, 0) + wr * 8192 +         \
            ((Q) * 32 + mi2 * 16 + c) * 64 + (((ks * 4 + g) ^ cg7) << 3));     \
    if ((Q) == 0) {                                                            \
      _Pragma("unroll") for (int ni = 0; ni < 4; ++ni)                         \
        _Pragma("unroll") for (int ks = 0; ks < 2; ++ks)                       \
          bfr[ni][ks] = *(const short8*)(lds + BB(BUF, 0) + (wc >> 1) * 8192 + \
              (brow + ni * 16 + c) * 64 + (((ks * 4 + g) ^ cg7) << 3));        \
    }                                                                          \
    STAGE_STMT;                                                                \
    __builtin_amdgcn_sched_barrier(0);                                         \
    __builtin_amdgcn_s_barrier();                                              \
    asm volatile("s_waitcnt lgkmcnt(0)" ::: "memory");                         \
    __builtin_amdgcn_sched_barrier(0);                                         \
    __builtin_amdgcn_s_setprio(1);                                             \
    _Pragma("unroll") for (int mi2 = 0; mi2 < 2; ++mi2)                        \
      _Pragma("unroll") for (int ni = 0; ni < 4; ++ni)                         \
        _Pragma("unroll") for (int ks = 0; ks < 2; ++ks)                       \
          acc[(Q) * 2 + mi2][ni] = __builtin_amdgcn_mfma_f32_16x16x32_bf16(    \
              afr[mi2][ks], bfr[ni][ks], acc[(Q) * 2 + mi2][ni], 0, 0, 0);     \
    __builtin_amdgcn_s_setprio(0);                                             \
    if (DO_VMCNT) {                                                            \
      asm volatile("s_waitcnt vmcnt(4)" ::: "memory");                         \
      __builtin_amdgcn_sched_barrier(0);                                       \
    }                                                                          \
    __builtin_amdgcn_s_barrier();                                              \
  }

  STAGE(A + (long)m0 * K, AB(0, 0));
  STAGE(A + (long)(m0 + 128) * K, AB(0, 1));
  STAGE(BT + (long)n0 * K, BB(0, 0));
  STAGE(BT + (long)(n0 + 128) * K, BB(0, 1));
  STAGE(BT + (long)n0 * K + 64, BB(1, 0));
  STAGE(BT + (long)(n0 + 128) * K + 64, BB(1, 1));
  asm volatile("s_waitcnt vmcnt(4)" ::: "memory");
  __builtin_amdgcn_sched_barrier(0);
  __builtin_amdgcn_s_barrier();

  for (int it2 = 0; it2 < nt / 2; ++it2) {
    const long T1 = (long)(2 * it2 + 1) * 64;
    const long T2 = (long)((2 * it2 + 2) & tmask) * 64;
    const long T3 = (long)((2 * it2 + 3) & tmask) * 64;
    PHASE(0, 0, STAGE(A + (long)m0 * K + T1, AB(1, 0)), false)
    PHASE(0, 1, STAGE(A + (long)(m0 + 128) * K + T1, AB(1, 1)), false)
    PHASE(0, 2, STAGE(BT + (long)n0 * K + T2, BB(0, 0)), false)
    PHASE(0, 3, STAGE(BT + (long)(n0 + 128) * K + T2, BB(0, 1)), true)
    PHASE(1, 0, STAGE(A + (long)m0 * K + T2, AB(0, 0)), false)
    PHASE(1, 1, STAGE(A + (long)(m0 + 128) * K + T2, AB(0, 1)), false)
    PHASE(1, 2, STAGE(BT + (long)n0 * K + T3, BB(1, 0)), false)
    PHASE(1, 3, STAGE(BT + (long)(n0 + 128) * K + T3, BB(1, 1)), true)
  }
#undef PHASE

#pragma unroll
  for (int mi = 0; mi < 8; ++mi)
#pragma unroll
    for (int ni = 0; ni < 4; ++ni)
#pragma unroll
      for (int j = 0; j < 4; ++j) {
        const int m = m0 + wr * 128 + mi * 16 + g * 4 + j;
        const int n = n0 + wc * 64 + ni * 16 + c;
        if (OUT_BF16)
          ((unsigned short*)Cout)[(long)m * N + n] = f2bf(acc[mi][ni][j]);
        else
          ((float*)Cout)[(long)m * N + n] = acc[mi][ni][j];
      }
}

// ---------------------------------------------------------------------------
// prep: qkv16 -> dense per-(b,h) attention operands in one pass.
//   qR [b,h][s][128]  rope'd + 1/sqrt(DH) prescale
//   kR [b,h][s][128]  rope'd
//   vT [b,h][d][s]    transposed V
// ---------------------------------------------------------------------------
__global__ __launch_bounds__(256) void prep_qkv(
    const unsigned short* __restrict__ qkv, const float* __restrict__ rope,
    const int* __restrict__ tpos, unsigned short* __restrict__ qR,
    unsigned short* __restrict__ kR, unsigned short* __restrict__ vTd) {
  __shared__ unsigned short t[64][136];
  const int s0 = blockIdx.x * 64, h = blockIdx.y, b = blockIdx.z;
  const int tid = threadIdx.x;
  const int r = tid >> 2;            // s-local 0..63
  const int qd = (tid & 3) * 32;     // d quarter
  const int s = s0 + r;
  const int pos = tpos[s];
  const long bh = (long)(b * Hn + h);
  const unsigned short* src = qkv + (long)(b * Sn + s) * QKVC + h * DHn + qd;
  const float4* pr = reinterpret_cast<const float4*>(rope) + (long)pos * 64 + (qd >> 1);

  union U8 { short8 v[4]; unsigned short u[32]; };
  U8 qi, ki, vi, qo, ko;
#pragma unroll
  for (int j = 0; j < 4; ++j) {
    qi.v[j] = *reinterpret_cast<const short8*>(src + j * 8);
    ki.v[j] = *reinterpret_cast<const short8*>(src + Dn + j * 8);
    vi.v[j] = *reinterpret_cast<const short8*>(src + 2 * Dn + j * 8);
  }
  const float sc = 0.08838834764831845f;  // 1/sqrt(128)
#pragma unroll
  for (int i = 0; i < 16; ++i) {
    const float4 pe = pr[i];
    const float qx = bf2f(qi.u[2 * i]), qy = bf2f(qi.u[2 * i + 1]);
    qo.u[2 * i]     = f2bf((pe.x * qx + pe.y * qy) * sc);
    qo.u[2 * i + 1] = f2bf((pe.z * qx + pe.w * qy) * sc);
    const float kx = bf2f(ki.u[2 * i]), ky = bf2f(ki.u[2 * i + 1]);
    ko.u[2 * i]     = f2bf(pe.x * kx + pe.y * ky);
    ko.u[2 * i + 1] = f2bf(pe.z * kx + pe.w * ky);
  }
  unsigned short* qdst = qR + (bh * Sn + s) * DHn + qd;
  unsigned short* kdst = kR + (bh * Sn + s) * DHn + qd;
#pragma unroll
  for (int j = 0; j < 4; ++j) {
    *reinterpret_cast<short8*>(qdst + j * 8) = qo.v[j];
    *reinterpret_cast<short8*>(kdst + j * 8) = ko.v[j];
    *reinterpret_cast<short8*>(&t[r][qd + j * 8]) = vi.v[j];
  }
  __syncthreads();
  const int d = tid >> 1, sb = (tid & 1) * 32;
  unsigned short* vdst = vTd + (bh * DHn + d) * Sn + s0 + sb;
#pragma unroll
  for (int it = 0; it < 4; ++it) {
    unsigned short o[8];
#pragma unroll
    for (int e = 0; e < 8; ++e) o[e] = t[sb + 8 * it + e][d];
    *reinterpret_cast<short8*>(vdst + 8 * it) = *reinterpret_cast<short8*>(&o[0]);
  }
}

// ---------------------------------------------------------------------------
// Flash attention: 4 waves/block, 64 q-rows, kv-tile 64, double-buffered
// gload_lds staging of K/V (XOR-window swizzled), counted-drain per tile.
// S^T = K*Q^T (softmax lane-local per q); PV: O^T = V^T * P^T.
// ---------------------------------------------------------------------------
__global__ __launch_bounds__(256, 2) void attn_mfma(
    const unsigned short* __restrict__ qR, const unsigned short* __restrict__ kR,
    const unsigned short* __restrict__ vTd, unsigned short* __restrict__ ctx) {
  __shared__ unsigned short lds[32768];   // K dbuf @0/8192, V dbuf @16384/24576
  __shared__ unsigned short Ps[4][16][72];
  const int qt = blockIdx.x, h = blockIdx.y, b = blockIdx.z;
  const int tid = threadIdx.x, wid = tid >> 6, lane = tid & 63;
  const int c = lane & 15, g = lane >> 4, cg7 = c & 7;
  const long bh = (long)(b * Hn + h);
  const unsigned short* kbase = kR + bh * Sn * DHn;
  const unsigned short* vbase = vTd + bh * DHn * Sn;

  short8 qf[4];
  {
    const unsigned short* qrow = qR + (bh * Sn + qt * 64 + wid * 16 + c) * DHn;
#pragma unroll
    for (int kc = 0; kc < 4; ++kc)
      qf[kc] = *reinterpret_cast<const short8*>(qrow + kc * 32 + g * 8);
  }

  // stage K tile [64 rows][16 windows] + V tile [128 rows][8 windows];
  // source window inverse-swizzled so swizzled ds_read sees logical layout
  auto STAGE = [&](int kt, int buf) {
#pragma unroll
    for (int j = 0; j < 4; ++j) {  // K: 1024 chunks
      const int ch = j * 256 + tid;
      const int r = ch >> 4, wd = ch & 15;
      const int ws = (wd & 8) | ((wd & 7) ^ (r & 7));
      gload16(kbase + (long)kt * 8192 + r * 128 + ws * 8,
              lds + buf * 8192 + j * 2048 + wid * 512);
    }
#pragma unroll
    for (int j = 0; j < 4; ++j) {  // V: 1024 chunks
      const int ch = j * 256 + tid;
      const int d = ch >> 3, sw = ch & 7;
      gload16(vbase + (long)d * Sn + kt * 64 + ((sw ^ (d & 7)) << 3),
              lds + 16384 + buf * 8192 + j * 2048 + wid * 512);
    }
  };

  float m = -INFINITY, lsum = 0.f;
  float4v ot[8];
#pragma unroll
  for (int fd = 0; fd < 8; ++fd) ot[fd] = (float4v){0.f, 0.f, 0.f, 0.f};

  STAGE(0, 0);
  __syncthreads();  // drains vmcnt(0) before barrier
  int cur = 0;

  for (int kt = 0; kt <= qt; ++kt) {
    if (kt < qt) STAGE(kt + 1, cur ^ 1);  // prefetch flies under compute

    // S^T = K * Q^T
    float4v scv[4];
#pragma unroll
    for (int f = 0; f < 4; ++f) scv[f] = (float4v){0.f, 0.f, 0.f, 0.f};
    __builtin_amdgcn_s_setprio(1);
#pragma unroll
    for (int f = 0; f < 4; ++f)
#pragma unroll
      for (int kc = 0; kc < 4; ++kc) {
        const int wp = kc * 4 + g;
        const int ws = (wp & 8) | ((wp & 7) ^ cg7);
        short8 kf = *reinterpret_cast<const short8*>(
            lds + cur * 8192 + (f * 16 + c) * 128 + ws * 8);
        scv[f] = __builtin_amdgcn_mfma_f32_16x16x32_bf16(kf, qf[kc], scv[f], 0, 0, 0);
      }
    __builtin_amdgcn_s_setprio(0);

    if (kt == qt) {
      const int qloc = wid * 16 + c;
#pragma unroll
      for (int f = 0; f < 4; ++f)
#pragma unroll
        for (int j = 0; j < 4; ++j)
          if (f * 16 + g * 4 + j > qloc) scv[f][j] = -INFINITY;
    }

    float tmax = -INFINITY;
#pragma unroll
    for (int f = 0; f < 4; ++f)
#pragma unroll
      for (int j = 0; j < 4; ++j) tmax = fmaxf(tmax, scv[f][j]);
    tmax = fmaxf(tmax, __shfl_xor(tmax, 16));
    tmax = fmaxf(tmax, __shfl_xor(tmax, 32));
    const float mnew = fmaxf(m, tmax);
    const float corr = __expf(m - mnew);
    float psum = 0.f;
#pragma unroll
    for (int f = 0; f < 4; ++f)
#pragma unroll
      for (int j = 0; j < 4; ++j) {
        scv[f][j] = __expf(scv[f][j] - mnew);
        psum += scv[f][j];
      }
    psum += __shfl_xor(psum, 16);
    psum += __shfl_xor(psum, 32);
    lsum = lsum * corr + psum;
    m = mnew;
#pragma unroll
    for (int fd = 0; fd < 8; ++fd) ot[fd] *= corr;

#pragma unroll
    for (int f = 0; f < 4; ++f) {
      unsigned int lo = (unsigned)f2bf(scv[f][0]) | ((unsigned)f2bf(scv[f][1]) << 16);
      unsigned int hi = (unsigned)f2bf(scv[f][2]) | ((unsigned)f2bf(scv[f][3]) << 16);
      uint2 pk; pk.x = lo; pk.y = hi;
      *reinterpret_cast<uint2*>(&Ps[wid][c][f * 16 + g * 4]) = pk;
    }

    short8 pf0 = *reinterpret_cast<const short8*>(&Ps[wid][c][g * 8]);
    short8 pf1 = *reinterpret_cast<const short8*>(&Ps[wid][c][32 + g * 8]);
    __builtin_amdgcn_s_setprio(1);
#pragma unroll
    for (int fd = 0; fd < 8; ++fd) {
      short8 vf0 = *reinterpret_cast<const short8*>(
          lds + 16384 + cur * 8192 + (fd * 16 + c) * 64 + ((g ^ cg7) << 3));
      short8 vf1 = *reinterpret_cast<const short8*>(
          lds + 16384 + cur * 8192 + (fd * 16 + c) * 64 + (((g + 4) ^ cg7) << 3));
      ot[fd] = __builtin_amdgcn_mfma_f32_16x16x32_bf16(vf0, pf0, ot[fd], 0, 0, 0);
      ot[fd] = __builtin_amdgcn_mfma_f32_16x16x32_bf16(vf1, pf1, ot[fd], 0, 0, 0);
    }
    __builtin_amdgcn_s_setprio(0);

    __syncthreads();  // drains this tile's prefetch (vmcnt 0) + barrier
    cur ^= 1;
  }

  const float inv = 1.0f / lsum;
  unsigned short* orow = ctx + (long)(b * Sn + qt * 64 + wid * 16 + c) * Dn + h * DHn;
#pragma unroll
  for (int fd = 0; fd < 8; ++fd) {
    const int d = fd * 16 + g * 4;
    uint2 pk;
    pk.x = (unsigned)f2bf(ot[fd][0] * inv) | ((unsigned)f2bf(ot[fd][1] * inv) << 16);
    pk.y = (unsigned)f2bf(ot[fd][2] * inv) | ((unsigned)f2bf(ot[fd][3] * inv) << 16);
    *reinterpret_cast<uint2*>(orow + d) = pk;
  }
}

// ---------------------------------------------------------------------------
extern "C" void kernel_launch(void* const* d_in, const int* in_sizes, int n_in,
                              void* d_out, int out_size, void* d_ws, size_t ws_size,
                              hipStream_t stream) {
  const float* x     = (const float*)d_in[0];
  const float* w_qkv = (const float*)d_in[1];
  const float* w_out = (const float*)d_in[2];
  const float* rope  = (const float*)d_in[3];
  const int*   tpos  = (const int*)d_in[4];
  float* out = (float*)d_out;

  unsigned short* x16   = (unsigned short*)d_ws;        // 8.4M sh (dead after QKV gemm)
  unsigned short* wqkvT = x16 + (size_t)BS * Dn;        // 12.6M sh (dead after QKV gemm)
  unsigned short* woutT = wqkvT + (size_t)Dn * QKVC;    // 4.2M sh (live till end)
  unsigned short* qkv16 = woutT + (size_t)Dn * Dn;      // 25.2M sh
  unsigned short* vT16  = qkv16 + (size_t)BS * QKVC;    // 8.4M sh
  unsigned short* ctx16 = vT16 + (size_t)BS * Dn;       // 8.4M sh
  unsigned short* qR    = x16;                          // alias (8.4M needed)
  unsigned short* kR    = wqkvT;                        // alias (8.4M of 12.6M)

  cvt_f32_bf16<<<(BS * Dn / 8 + 255) / 256, 256, 0, stream>>>(x, x16, BS * Dn / 8);
  {
    dim3 g1(QKVC / 64, Dn / 64);
    transpose_cvt<<<g1, 256, 0, stream>>>(w_qkv, wqkvT, Dn, QKVC);
    dim3 g2(Dn / 64, Dn / 64);
    transpose_cvt<<<g2, 256, 0, stream>>>(w_out, woutT, Dn, Dn);
  }
  {
    dim3 grid(QKVC / 256, BS / 256);  // 24 x 16 = 384
    gemm8p<true><<<grid, 512, 0, stream>>>(x16, wqkvT, qkv16, BS, QKVC, Dn);
  }
  {
    dim3 grid(Sn / 64, Hn, Bn);
    prep_qkv<<<grid, 256, 0, stream>>>(qkv16, rope, tpos, qR, kR, vT16);
  }
  {
    dim3 grid(Sn / 64, Hn, Bn);
    attn_mfma<<<grid, 256, 0, stream>>>(qR, kR, vT16, ctx16);
  }
  {
    dim3 grid(Dn / 256, BS / 256);    // 8 x 16 = 128
    gemm8p<false><<<grid, 512, 0, stream>>>(ctx16, woutT, out, BS, Dn, Dn);
  }
}

// Round 6
// 279.688 us; speedup vs baseline: 16.4013x; 1.0109x over previous
//
#include <hip/hip_runtime.h>
#include <hip/hip_bf16.h>
#include <math.h>

#define Bn 4
#define Sn 1024
#define Dn 2048
#define Hn 16
#define DHn 128
#define BS (Bn * Sn)       // 4096
#define QKVC (3 * Dn)      // 6144

typedef __attribute__((ext_vector_type(8))) short short8;   // 8 x bf16
typedef __attribute__((ext_vector_type(4))) float float4v;  // MFMA acc

// f32 -> bf16 (round-to-nearest-even)
__device__ inline unsigned short f2bf(float x) {
  union { float f; unsigned int u; } v; v.f = x;
  unsigned int r = v.u + 0x7fffu + ((v.u >> 16) & 1u);
  return (unsigned short)(r >> 16);
}
__device__ inline float bf2f(unsigned short b) {
  union { unsigned int u; float f; } v; v.u = ((unsigned int)b) << 16;
  return v.f;
}

// async global->LDS, 16B per lane. LDS dest = wave-uniform base + lane*16.
__device__ __forceinline__ void gload16(const unsigned short* g, unsigned short* l) {
  __builtin_amdgcn_global_load_lds(
      (const __attribute__((address_space(1))) unsigned int*)g,
      (__attribute__((address_space(3))) unsigned int*)l, 16, 0, 0);
}

// ---------------------------------------------------------------------------
// x f32 -> bf16, 8 elems/thread
// ---------------------------------------------------------------------------
__global__ __launch_bounds__(256) void cvt_f32_bf16(
    const float* __restrict__ in, unsigned short* __restrict__ out, int n8) {
  int id = blockIdx.x * 256 + threadIdx.x;
  if (id >= n8) return;
  const float4* p = reinterpret_cast<const float4*>(in) + 2 * (size_t)id;
  float4 a = p[0], b = p[1];
  short8 o;
  o[0] = (short)f2bf(a.x); o[1] = (short)f2bf(a.y);
  o[2] = (short)f2bf(a.z); o[3] = (short)f2bf(a.w);
  o[4] = (short)f2bf(b.x); o[5] = (short)f2bf(b.y);
  o[6] = (short)f2bf(b.z); o[7] = (short)f2bf(b.w);
  *reinterpret_cast<short8*>(out + 8 * (size_t)id) = o;
}

// ---------------------------------------------------------------------------
// Weight transpose+convert: w [K][N] f32 -> wT [N][K] bf16. 64x64 tiles.
// ---------------------------------------------------------------------------
__global__ __launch_bounds__(256) void transpose_cvt(
    const float* __restrict__ w, unsigned short* __restrict__ wT, int K, int N) {
  __shared__ unsigned short t[64][72];
  const int c0 = blockIdx.x * 64;  // N
  const int r0 = blockIdx.y * 64;  // K
  const int tid = threadIdx.x;
  const int r = tid >> 2;
  const int cb = (tid & 3) * 16;
#pragma unroll
  for (int it = 0; it < 4; ++it) {
    float4 v = *reinterpret_cast<const float4*>(&w[(long)(r0 + r) * N + c0 + cb + 4 * it]);
    t[r][cb + 4 * it + 0] = f2bf(v.x);
    t[r][cb + 4 * it + 1] = f2bf(v.y);
    t[r][cb + 4 * it + 2] = f2bf(v.z);
    t[r][cb + 4 * it + 3] = f2bf(v.w);
  }
  __syncthreads();
  unsigned short o[16];
#pragma unroll
  for (int e = 0; e < 16; ++e) o[e] = t[cb + e][r];
  unsigned short* dst = &wT[(long)(c0 + r) * K + r0 + cb];
  *reinterpret_cast<short8*>(dst) = *reinterpret_cast<short8*>(&o[0]);
  *reinterpret_cast<short8*>(dst + 8) = *reinterpret_cast<short8*>(&o[8]);
}

// ---------------------------------------------------------------------------
// 256x128-tile pipelined bf16 MFMA GEMM: C = A[M,K] * BT[N,K]^T.
// 512 thr = 8 waves (4M x 2N), 64x64/wave. BK=64. LDS 96 KiB:
//   A: 2 bufs x 2 halves x [128][64]   B: 2 bufs x [128][64]
// XOR-window swizzle (pre-swizzled source + linear gload_lds + swizzled read).
// Counted vmcnt(2) twice per 2-tile iter; A staged 1 tile ahead, B 1.5.
// ---------------------------------------------------------------------------
#define AB8(buf, h) ((buf) * 16384 + (h) * 8192)      // shorts
#define BB8(buf) (32768 + (buf) * 8192)               // shorts

template <bool OUT_BF16>
__global__ __launch_bounds__(512, 2) void gemm_pipe(
    const unsigned short* __restrict__ A, const unsigned short* __restrict__ BT,
    void* __restrict__ Cout, int M, int N, int K) {
  __shared__ unsigned short lds[49152];  // 96 KiB
  const int tid = threadIdx.x;
  const int wid = tid >> 6, lane = tid & 63;
  const int c = lane & 15, g = lane >> 4;
  const int wr = wid >> 1, wc = wid & 1;   // 4M x 2N waves
  const int cg7 = c & 7;

  // XCD-aware block swizzle; grid: x = M/256, y = N/128 (consecutive bids
  // within an XCD chunk share the B weight panel)
  const int nwg = gridDim.x * gridDim.y;
  const int bid = blockIdx.y * gridDim.x + blockIdx.x;
  const int swz = (bid & 7) * (nwg >> 3) + (bid >> 3);
  const int m0 = (swz % gridDim.x) * 256, n0 = (swz / gridDim.x) * 128;

  const int nt = K >> 6;
  const int tmask = nt - 1;

  float4v acc[4][4];
#pragma unroll
  for (int i = 0; i < 4; ++i)
#pragma unroll
    for (int j = 0; j < 4; ++j) acc[i][j] = (float4v){0.f, 0.f, 0.f, 0.f};
  short8 bfr[4][2];

  // stage one 128x64 block; source window inverse-swizzled
  auto STAGE = [&](const unsigned short* gbase, int sbase) {
#pragma unroll
    for (int j = 0; j < 2; ++j) {
      const int ch = j * 512 + tid;
      const int r = ch >> 3;
      const int wo = (ch & 7) ^ (r & 7);
      gload16(gbase + (long)r * K + wo * 8, lds + sbase + j * 4096 + wid * 512);
    }
  };

#define PHASE(BUF, MIH, STAGE_STMT, DO_VMCNT)                                  \
  {                                                                            \
    __builtin_amdgcn_sched_barrier(0);                                         \
    short8 afr[2][2];                                                          \
    _Pragma("unroll") for (int mi2 = 0; mi2 < 2; ++mi2) {                      \
      const int mrow = wr * 64 + ((MIH) * 2 + mi2) * 16;                       \
      const int hh = mrow >> 7;                                                \
      const int rl = (mrow & 127) + c;                                         \
      _Pragma("unroll") for (int ks = 0; ks < 2; ++ks)                         \
        afr[mi2][ks] = *(const short8*)(lds + AB8(BUF, 0) + hh * 8192 +        \
            rl * 64 + (((ks * 4 + g) ^ cg7) << 3));                            \
    }                                                                          \
    if ((MIH) == 0) {                                                          \
      _Pragma("unroll") for (int ni = 0; ni < 4; ++ni)                         \
        _Pragma("unroll") for (int ks = 0; ks < 2; ++ks)                       \
          bfr[ni][ks] = *(const short8*)(lds + BB8(BUF) +                      \
              (wc * 64 + ni * 16 + c) * 64 + (((ks * 4 + g) ^ cg7) << 3));     \
    }                                                                          \
    STAGE_STMT;                                                                \
    __builtin_amdgcn_sched_barrier(0);                                         \
    __builtin_amdgcn_s_barrier();                                              \
    asm volatile("s_waitcnt lgkmcnt(0)" ::: "memory");                         \
    __builtin_amdgcn_sched_barrier(0);                                         \
    __builtin_amdgcn_s_setprio(1);                                             \
    _Pragma("unroll") for (int mi2 = 0; mi2 < 2; ++mi2)                        \
      _Pragma("unroll") for (int ni = 0; ni < 4; ++ni)                         \
        _Pragma("unroll") for (int ks = 0; ks < 2; ++ks)                       \
          acc[(MIH) * 2 + mi2][ni] = __builtin_amdgcn_mfma_f32_16x16x32_bf16(  \
              afr[mi2][ks], bfr[ni][ks], acc[(MIH) * 2 + mi2][ni], 0, 0, 0);   \
    __builtin_amdgcn_s_setprio(0);                                             \
    if (DO_VMCNT) {                                                            \
      asm volatile("s_waitcnt vmcnt(2)" ::: "memory");                         \
      __builtin_amdgcn_sched_barrier(0);                                       \
    }                                                                          \
    __builtin_amdgcn_s_barrier();                                              \
  }

  // Prologue: A(0) both halves, B(0), B(1); leave B(1) in flight.
  STAGE(A + (long)m0 * K, AB8(0, 0));
  STAGE(A + (long)(m0 + 128) * K, AB8(0, 1));
  STAGE(BT + (long)n0 * K, BB8(0));
  STAGE(BT + (long)n0 * K + 64, BB8(1));
  asm volatile("s_waitcnt vmcnt(2)" ::: "memory");
  __builtin_amdgcn_sched_barrier(0);
  __builtin_amdgcn_s_barrier();

  for (int it2 = 0; it2 < nt / 2; ++it2) {
    const long T1 = (long)(2 * it2 + 1) * 64;
    const long T2 = (long)((2 * it2 + 2) & tmask) * 64;
    const long T3 = (long)((2 * it2 + 3) & tmask) * 64;
    PHASE(0, 0, STAGE(A + (long)m0 * K + T1, AB8(1, 0)), false)
    PHASE(0, 1,
          { STAGE(A + (long)(m0 + 128) * K + T1, AB8(1, 1));
            STAGE(BT + (long)n0 * K + T2, BB8(0)); }, true)
    PHASE(1, 0, STAGE(A + (long)m0 * K + T2, AB8(0, 0)), false)
    PHASE(1, 1,
          { STAGE(A + (long)(m0 + 128) * K + T2, AB8(0, 1));
            STAGE(BT + (long)n0 * K + T3, BB8(1)); }, true)
  }
#undef PHASE

#pragma unroll
  for (int mi = 0; mi < 4; ++mi)
#pragma unroll
    for (int ni = 0; ni < 4; ++ni)
#pragma unroll
      for (int j = 0; j < 4; ++j) {
        const int m = m0 + wr * 64 + mi * 16 + g * 4 + j;
        const int n = n0 + wc * 64 + ni * 16 + c;
        if (OUT_BF16)
          ((unsigned short*)Cout)[(long)m * N + n] = f2bf(acc[mi][ni][j]);
        else
          ((float*)Cout)[(long)m * N + n] = acc[mi][ni][j];
      }
}

// ---------------------------------------------------------------------------
// prep: qkv16 -> dense per-(b,h) attention operands in one pass.
//   qR [b,h][s][128]  rope'd, scaled by log2(e)/sqrt(DH)  (exp2 domain)
//   kR [b,h][s][128]  rope'd
//   vT [b,h][d][s]    transposed V
// ---------------------------------------------------------------------------
__global__ __launch_bounds__(256) void prep_qkv(
    const unsigned short* __restrict__ qkv, const float* __restrict__ rope,
    const int* __restrict__ tpos, unsigned short* __restrict__ qR,
    unsigned short* __restrict__ kR, unsigned short* __restrict__ vTd) {
  __shared__ unsigned short t[64][136];
  const int s0 = blockIdx.x * 64, h = blockIdx.y, b = blockIdx.z;
  const int tid = threadIdx.x;
  const int r = tid >> 2;            // s-local 0..63
  const int qd = (tid & 3) * 32;     // d quarter
  const int s = s0 + r;
  const int pos = tpos[s];
  const long bh = (long)(b * Hn + h);
  const unsigned short* src = qkv + (long)(b * Sn + s) * QKVC + h * DHn + qd;
  const float4* pr = reinterpret_cast<const float4*>(rope) + (long)pos * 64 + (qd >> 1);

  union U8 { short8 v[4]; unsigned short u[32]; };
  U8 qi, ki, vi, qo, ko;
#pragma unroll
  for (int j = 0; j < 4; ++j) {
    qi.v[j] = *reinterpret_cast<const short8*>(src + j * 8);
    ki.v[j] = *reinterpret_cast<const short8*>(src + Dn + j * 8);
    vi.v[j] = *reinterpret_cast<const short8*>(src + 2 * Dn + j * 8);
  }
  const float sc = 0.1275174213f;  // log2(e)/sqrt(128)
#pragma unroll
  for (int i = 0; i < 16; ++i) {
    const float4 pe = pr[i];
    const float qx = bf2f(qi.u[2 * i]), qy = bf2f(qi.u[2 * i + 1]);
    qo.u[2 * i]     = f2bf((pe.x * qx + pe.y * qy) * sc);
    qo.u[2 * i + 1] = f2bf((pe.z * qx + pe.w * qy) * sc);
    const float kx = bf2f(ki.u[2 * i]), ky = bf2f(ki.u[2 * i + 1]);
    ko.u[2 * i]     = f2bf(pe.x * kx + pe.y * ky);
    ko.u[2 * i + 1] = f2bf(pe.z * kx + pe.w * ky);
  }
  unsigned short* qdst = qR + (bh * Sn + s) * DHn + qd;
  unsigned short* kdst = kR + (bh * Sn + s) * DHn + qd;
#pragma unroll
  for (int j = 0; j < 4; ++j) {
    *reinterpret_cast<short8*>(qdst + j * 8) = qo.v[j];
    *reinterpret_cast<short8*>(kdst + j * 8) = ko.v[j];
    *reinterpret_cast<short8*>(&t[r][qd + j * 8]) = vi.v[j];
  }
  __syncthreads();
  const int d = tid >> 1, sb = (tid & 1) * 32;
  unsigned short* vdst = vTd + (bh * DHn + d) * Sn + s0 + sb;
#pragma unroll
  for (int it = 0; it < 4; ++it) {
    unsigned short o[8];
#pragma unroll
    for (int e = 0; e < 8; ++e) o[e] = t[sb + 8 * it + e][d];
    *reinterpret_cast<short8*>(vdst + 8 * it) = *reinterpret_cast<short8*>(&o[0]);
  }
}

// ---------------------------------------------------------------------------
// Flash attention: 4 waves/block, 64 q-rows, kv-tile 64, double-buffered
// gload_lds staging of K/V (XOR-window swizzled). Softmax in exp2 domain,
// defer-max (T13). Heavy qt blocks dispatched first (reverse map).
// ---------------------------------------------------------------------------
__global__ __launch_bounds__(256, 2) void attn_mfma(
    const unsigned short* __restrict__ qR, const unsigned short* __restrict__ kR,
    const unsigned short* __restrict__ vTd, unsigned short* __restrict__ ctx) {
  __shared__ unsigned short lds[32768];   // K dbuf @0/8192, V dbuf @16384/24576
  __shared__ unsigned short Ps[4][16][72];
  const int qt = gridDim.x - 1 - blockIdx.x;  // heavy blocks first
  const int h = blockIdx.y, b = blockIdx.z;
  const int tid = threadIdx.x, wid = tid >> 6, lane = tid & 63;
  const int c = lane & 15, g = lane >> 4, cg7 = c & 7;
  const long bh = (long)(b * Hn + h);
  const unsigned short* kbase = kR + bh * Sn * DHn;
  const unsigned short* vbase = vTd + bh * DHn * Sn;

  short8 qf[4];
  {
    const unsigned short* qrow = qR + (bh * Sn + qt * 64 + wid * 16 + c) * DHn;
#pragma unroll
    for (int kc = 0; kc < 4; ++kc)
      qf[kc] = *reinterpret_cast<const short8*>(qrow + kc * 32 + g * 8);
  }

  auto STAGE = [&](int kt, int buf) {
#pragma unroll
    for (int j = 0; j < 4; ++j) {  // K tile [64][128]
      const int ch = j * 256 + tid;
      const int r = ch >> 4, wd = ch & 15;
      const int ws = (wd & 8) | ((wd & 7) ^ (r & 7));
      gload16(kbase + (long)kt * 8192 + r * 128 + ws * 8,
              lds + buf * 8192 + j * 2048 + wid * 512);
    }
#pragma unroll
    for (int j = 0; j < 4; ++j) {  // V^T tile [128][64]
      const int ch = j * 256 + tid;
      const int d = ch >> 3, sw = ch & 7;
      gload16(vbase + (long)d * Sn + kt * 64 + ((sw ^ (d & 7)) << 3),
              lds + 16384 + buf * 8192 + j * 2048 + wid * 512);
    }
  };

  float m = -INFINITY, lsum = 0.f;
  float4v ot[8];
#pragma unroll
  for (int fd = 0; fd < 8; ++fd) ot[fd] = (float4v){0.f, 0.f, 0.f, 0.f};

  STAGE(0, 0);
  __syncthreads();
  int cur = 0;

  for (int kt = 0; kt <= qt; ++kt) {
    if (kt < qt) STAGE(kt + 1, cur ^ 1);  // prefetch flies under compute

    float4v scv[4];
#pragma unroll
    for (int f = 0; f < 4; ++f) scv[f] = (float4v){0.f, 0.f, 0.f, 0.f};
    __builtin_amdgcn_s_setprio(1);
#pragma unroll
    for (int f = 0; f < 4; ++f)
#pragma unroll
      for (int kc = 0; kc < 4; ++kc) {
        const int wp = kc * 4 + g;
        const int ws = (wp & 8) | ((wp & 7) ^ cg7);
        short8 kf = *reinterpret_cast<const short8*>(
            lds + cur * 8192 + (f * 16 + c) * 128 + ws * 8);
        scv[f] = __builtin_amdgcn_mfma_f32_16x16x32_bf16(kf, qf[kc], scv[f], 0, 0, 0);
      }
    __builtin_amdgcn_s_setprio(0);

    if (kt == qt) {
      const int qloc = wid * 16 + c;
#pragma unroll
      for (int f = 0; f < 4; ++f)
#pragma unroll
        for (int j = 0; j < 4; ++j)
          if (f * 16 + g * 4 + j > qloc) scv[f][j] = -INFINITY;
    }

    float tmax = -INFINITY;
#pragma unroll
    for (int f = 0; f < 4; ++f)
#pragma unroll
      for (int j = 0; j < 4; ++j) tmax = fmaxf(tmax, scv[f][j]);
    tmax = fmaxf(tmax, __shfl_xor(tmax, 16));
    tmax = fmaxf(tmax, __shfl_xor(tmax, 32));

    float mnew, corr;
    if (__all(tmax <= m + 8.f)) {         // defer-max: skip rescale
      mnew = m; corr = 1.f;
    } else {
      mnew = fmaxf(m, tmax);
      corr = exp2f(m - mnew);
#pragma unroll
      for (int fd = 0; fd < 8; ++fd) ot[fd] *= corr;
    }
    float psum = 0.f;
#pragma unroll
    for (int f = 0; f < 4; ++f)
#pragma unroll
      for (int j = 0; j < 4; ++j) {
        scv[f][j] = exp2f(scv[f][j] - mnew);
        psum += scv[f][j];
      }
    psum += __shfl_xor(psum, 16);
    psum += __shfl_xor(psum, 32);
    lsum = lsum * corr + psum;
    m = mnew;

#pragma unroll
    for (int f = 0; f < 4; ++f) {
      unsigned int lo = (unsigned)f2bf(scv[f][0]) | ((unsigned)f2bf(scv[f][1]) << 16);
      unsigned int hi = (unsigned)f2bf(scv[f][2]) | ((unsigned)f2bf(scv[f][3]) << 16);
      uint2 pk; pk.x = lo; pk.y = hi;
      *reinterpret_cast<uint2*>(&Ps[wid][c][f * 16 + g * 4]) = pk;
    }

    short8 pf0 = *reinterpret_cast<const short8*>(&Ps[wid][c][g * 8]);
    short8 pf1 = *reinterpret_cast<const short8*>(&Ps[wid][c][32 + g * 8]);
    __builtin_amdgcn_s_setprio(1);
#pragma unroll
    for (int fd = 0; fd < 8; ++fd) {
      short8 vf0 = *reinterpret_cast<const short8*>(
          lds + 16384 + cur * 8192 + (fd * 16 + c) * 64 + ((g ^ cg7) << 3));
      short8 vf1 = *reinterpret_cast<const short8*>(
          lds + 16384 + cur * 8192 + (fd * 16 + c) * 64 + (((g + 4) ^ cg7) << 3));
      ot[fd] = __builtin_amdgcn_mfma_f32_16x16x32_bf16(vf0, pf0, ot[fd], 0, 0, 0);
      ot[fd] = __builtin_amdgcn_mfma_f32_16x16x32_bf16(vf1, pf1, ot[fd], 0, 0, 0);
    }
    __builtin_amdgcn_s_setprio(0);

    __syncthreads();  // drains this tile's prefetch + barrier
    cur ^= 1;
  }

  const float inv = 1.0f / lsum;
  unsigned short* orow = ctx + (long)(b * Sn + qt * 64 + wid * 16 + c) * Dn + h * DHn;
#pragma unroll
  for (int fd = 0; fd < 8; ++fd) {
    const int d = fd * 16 + g * 4;
    uint2 pk;
    pk.x = (unsigned)f2bf(ot[fd][0] * inv) | ((unsigned)f2bf(ot[fd][1] * inv) << 16);
    pk.y = (unsigned)f2bf(ot[fd][2] * inv) | ((unsigned)f2bf(ot[fd][3] * inv) << 16);
    *reinterpret_cast<uint2*>(orow + d) = pk;
  }
}

// ---------------------------------------------------------------------------
extern "C" void kernel_launch(void* const* d_in, const int* in_sizes, int n_in,
                              void* d_out, int out_size, void* d_ws, size_t ws_size,
                              hipStream_t stream) {
  const float* x     = (const float*)d_in[0];
  const float* w_qkv = (const float*)d_in[1];
  const float* w_out = (const float*)d_in[2];
  const float* rope  = (const float*)d_in[3];
  const int*   tpos  = (const int*)d_in[4];
  float* out = (float*)d_out;

  unsigned short* x16   = (unsigned short*)d_ws;        // dead after QKV gemm
  unsigned short* wqkvT = x16 + (size_t)BS * Dn;        // dead after QKV gemm
  unsigned short* woutT = wqkvT + (size_t)Dn * QKVC;
  unsigned short* qkv16 = woutT + (size_t)Dn * Dn;
  unsigned short* vT16  = qkv16 + (size_t)BS * QKVC;
  unsigned short* ctx16 = vT16 + (size_t)BS * Dn;
  unsigned short* qR    = x16;                          // alias
  unsigned short* kR    = wqkvT;                        // alias

  cvt_f32_bf16<<<(BS * Dn / 8 + 255) / 256, 256, 0, stream>>>(x, x16, BS * Dn / 8);
  {
    dim3 g1(QKVC / 64, Dn / 64);
    transpose_cvt<<<g1, 256, 0, stream>>>(w_qkv, wqkvT, Dn, QKVC);
    dim3 g2(Dn / 64, Dn / 64);
    transpose_cvt<<<g2, 256, 0, stream>>>(w_out, woutT, Dn, Dn);
  }
  {
    dim3 grid(BS / 256, QKVC / 128);  // 16 x 48 = 768 = 3.0 rounds
    gemm_pipe<true><<<grid, 512, 0, stream>>>(x16, wqkvT, qkv16, BS, QKVC, Dn);
  }
  {
    dim3 grid(Sn / 64, Hn, Bn);
    prep_qkv<<<grid, 256, 0, stream>>>(qkv16, rope, tpos, qR, kR, vT16);
  }
  {
    dim3 grid(Sn / 64, Hn, Bn);
    attn_mfma<<<grid, 256, 0, stream>>>(qR, kR, vT16, ctx16);
  }
  {
    dim3 grid(BS / 256, Dn / 128);    // 16 x 16 = 256 = 1.0 round
    gemm_pipe<false><<<grid, 512, 0, stream>>>(ctx16, woutT, out, BS, Dn, Dn);
  }
}

// Round 7
// 271.387 us; speedup vs baseline: 16.9030x; 1.0306x over previous
//
#include <hip/hip_runtime.h>
#include <hip/hip_bf16.h>
#include <math.h>

#define Bn 4
#define Sn 1024
#define Dn 2048
#define Hn 16
#define DHn 128
#define BS (Bn * Sn)       // 4096
#define QKVC (3 * Dn)      // 6144

typedef __attribute__((ext_vector_type(8))) short short8;   // 8 x bf16
typedef __attribute__((ext_vector_type(4))) float float4v;  // MFMA acc

// f32 -> bf16 (round-to-nearest-even)
__device__ inline unsigned short f2bf(float x) {
  union { float f; unsigned int u; } v; v.f = x;
  unsigned int r = v.u + 0x7fffu + ((v.u >> 16) & 1u);
  return (unsigned short)(r >> 16);
}
__device__ inline float bf2f(unsigned short b) {
  union { unsigned int u; float f; } v; v.u = ((unsigned int)b) << 16;
  return v.f;
}

// async global->LDS, 16B per lane. LDS dest = wave-uniform base + lane*16.
__device__ __forceinline__ void gload16(const unsigned short* g, unsigned short* l) {
  __builtin_amdgcn_global_load_lds(
      (const __attribute__((address_space(1))) unsigned int*)g,
      (__attribute__((address_space(3))) unsigned int*)l, 16, 0, 0);
}

// ---------------------------------------------------------------------------
// x f32 -> bf16, 8 elems/thread
// ---------------------------------------------------------------------------
__global__ __launch_bounds__(256) void cvt_f32_bf16(
    const float* __restrict__ in, unsigned short* __restrict__ out, int n8) {
  int id = blockIdx.x * 256 + threadIdx.x;
  if (id >= n8) return;
  const float4* p = reinterpret_cast<const float4*>(in) + 2 * (size_t)id;
  float4 a = p[0], b = p[1];
  short8 o;
  o[0] = (short)f2bf(a.x); o[1] = (short)f2bf(a.y);
  o[2] = (short)f2bf(a.z); o[3] = (short)f2bf(a.w);
  o[4] = (short)f2bf(b.x); o[5] = (short)f2bf(b.y);
  o[6] = (short)f2bf(b.z); o[7] = (short)f2bf(b.w);
  *reinterpret_cast<short8*>(out + 8 * (size_t)id) = o;
}

// ---------------------------------------------------------------------------
// Weight transpose+convert: w [K][N] f32 -> wT [N][K] bf16. 64x64 tiles.
// ---------------------------------------------------------------------------
__global__ __launch_bounds__(256) void transpose_cvt(
    const float* __restrict__ w, unsigned short* __restrict__ wT, int K, int N) {
  __shared__ unsigned short t[64][72];
  const int c0 = blockIdx.x * 64;  // N
  const int r0 = blockIdx.y * 64;  // K
  const int tid = threadIdx.x;
  const int r = tid >> 2;
  const int cb = (tid & 3) * 16;
#pragma unroll
  for (int it = 0; it < 4; ++it) {
    float4 v = *reinterpret_cast<const float4*>(&w[(long)(r0 + r) * N + c0 + cb + 4 * it]);
    t[r][cb + 4 * it + 0] = f2bf(v.x);
    t[r][cb + 4 * it + 1] = f2bf(v.y);
    t[r][cb + 4 * it + 2] = f2bf(v.z);
    t[r][cb + 4 * it + 3] = f2bf(v.w);
  }
  __syncthreads();
  unsigned short o[16];
#pragma unroll
  for (int e = 0; e < 16; ++e) o[e] = t[cb + e][r];
  unsigned short* dst = &wT[(long)(c0 + r) * K + r0 + cb];
  *reinterpret_cast<short8*>(dst) = *reinterpret_cast<short8*>(&o[0]);
  *reinterpret_cast<short8*>(dst + 8) = *reinterpret_cast<short8*>(&o[8]);
}

// ---------------------------------------------------------------------------
// Shared 256x128-tile pipelined main-loop phase (R6 structure, verified).
// 512 thr = 8 waves (4M x 2N), 64x64/wave, BK=64, LDS 96 KiB.
// ---------------------------------------------------------------------------
#define AB8(buf, h) ((buf) * 16384 + (h) * 8192)      // shorts
#define BB8(buf) (32768 + (buf) * 8192)               // shorts

#define PHASE(BUF, MIH, STAGE_STMT, DO_VMCNT)                                  \
  {                                                                            \
    __builtin_amdgcn_sched_barrier(0);                                         \
    short8 afr[2][2];                                                          \
    _Pragma("unroll") for (int mi2 = 0; mi2 < 2; ++mi2) {                      \
      const int mrow = wr * 64 + ((MIH) * 2 + mi2) * 16;                       \
      const int hh = mrow >> 7;                                                \
      const int rl = (mrow & 127) + c;                                         \
      _Pragma("unroll") for (int ks = 0; ks < 2; ++ks)                         \
        afr[mi2][ks] = *(const short8*)(lds + AB8(BUF, 0) + hh * 8192 +        \
            rl * 64 + (((ks * 4 + g) ^ cg7) << 3));                            \
    }                                                                          \
    if ((MIH) == 0) {                                                          \
      _Pragma("unroll") for (int ni = 0; ni < 4; ++ni)                         \
        _Pragma("unroll") for (int ks = 0; ks < 2; ++ks)                       \
          bfr[ni][ks] = *(const short8*)(lds + BB8(BUF) +                      \
              (wc * 64 + ni * 16 + c) * 64 + (((ks * 4 + g) ^ cg7) << 3));     \
    }                                                                          \
    STAGE_STMT;                                                                \
    __builtin_amdgcn_sched_barrier(0);                                         \
    __builtin_amdgcn_s_barrier();                                              \
    asm volatile("s_waitcnt lgkmcnt(0)" ::: "memory");                         \
    __builtin_amdgcn_sched_barrier(0);                                         \
    __builtin_amdgcn_s_setprio(1);                                             \
    _Pragma("unroll") for (int mi2 = 0; mi2 < 2; ++mi2)                        \
      _Pragma("unroll") for (int ni = 0; ni < 4; ++ni)                         \
        _Pragma("unroll") for (int ks = 0; ks < 2; ++ks)                       \
          acc[(MIH) * 2 + mi2][ni] = __builtin_amdgcn_mfma_f32_16x16x32_bf16(  \
              afr[mi2][ks], bfr[ni][ks], acc[(MIH) * 2 + mi2][ni], 0, 0, 0);   \
    __builtin_amdgcn_s_setprio(0);                                             \
    if (DO_VMCNT) {                                                            \
      asm volatile("s_waitcnt vmcnt(2)" ::: "memory");                         \
      __builtin_amdgcn_sched_barrier(0);                                       \
    }                                                                          \
    __builtin_amdgcn_s_barrier();                                              \
  }

#define GEMM_MAIN_LOOP(A_, BT_, K_)                                            \
  STAGE(A_ + (long)m0 * K_, AB8(0, 0));                                        \
  STAGE(A_ + (long)(m0 + 128) * K_, AB8(0, 1));                                \
  STAGE(BT_ + (long)n0 * K_, BB8(0));                                          \
  STAGE(BT_ + (long)n0 * K_ + 64, BB8(1));                                     \
  asm volatile("s_waitcnt vmcnt(2)" ::: "memory");                             \
  __builtin_amdgcn_sched_barrier(0);                                           \
  __builtin_amdgcn_s_barrier();                                                \
  for (int it2 = 0; it2 < nt / 2; ++it2) {                                     \
    const long T1 = (long)(2 * it2 + 1) * 64;                                  \
    const long T2 = (long)((2 * it2 + 2) & tmask) * 64;                        \
    const long T3 = (long)((2 * it2 + 3) & tmask) * 64;                        \
    PHASE(0, 0, STAGE(A_ + (long)m0 * K_ + T1, AB8(1, 0)), false)              \
    PHASE(0, 1,                                                                \
          { STAGE(A_ + (long)(m0 + 128) * K_ + T1, AB8(1, 1));                 \
            STAGE(BT_ + (long)n0 * K_ + T2, BB8(0)); }, true)                  \
    PHASE(1, 0, STAGE(A_ + (long)m0 * K_ + T2, AB8(0, 0)), false)              \
    PHASE(1, 1,                                                                \
          { STAGE(A_ + (long)(m0 + 128) * K_ + T2, AB8(0, 1));                 \
            STAGE(BT_ + (long)n0 * K_ + T3, BB8(1)); }, true)                  \
  }

// ---------------------------------------------------------------------------
// QKV GEMM with fused rope + head-split epilogue.
// Tile 256x128: n-panel = exactly one head's 128 d's of q, k or v.
//   q -> qR [bh][s][128] rope'd, scaled log2(e)/sqrt(DH)
//   k -> kR [bh][s][128] rope'd
//   v -> vStage [bh][s][128] (direct store; transposed by transpose_v)
// ---------------------------------------------------------------------------
__global__ __launch_bounds__(512, 2) void gemm_qkv(
    const unsigned short* __restrict__ A, const unsigned short* __restrict__ BT,
    const float* __restrict__ rope, const int* __restrict__ tpos,
    unsigned short* __restrict__ qR, unsigned short* __restrict__ kR,
    unsigned short* __restrict__ vStage, int K) {
  __shared__ unsigned short lds[49152];  // 96 KiB
  const int tid = threadIdx.x;
  const int wid = tid >> 6, lane = tid & 63;
  const int c = lane & 15, g = lane >> 4;
  const int wr = wid >> 1, wc = wid & 1;
  const int cg7 = c & 7;

  const int nwg = gridDim.x * gridDim.y;
  const int bid = blockIdx.y * gridDim.x + blockIdx.x;
  const int swz = (bid & 7) * (nwg >> 3) + (bid >> 3);
  const int m0 = (swz % gridDim.x) * 256, n0 = (swz / gridDim.x) * 128;

  const int nt = K >> 6;
  const int tmask = nt - 1;

  float4v acc[4][4];
#pragma unroll
  for (int i = 0; i < 4; ++i)
#pragma unroll
    for (int j = 0; j < 4; ++j) acc[i][j] = (float4v){0.f, 0.f, 0.f, 0.f};
  short8 bfr[4][2];

  auto STAGE = [&](const unsigned short* gbase, int sbase) {
#pragma unroll
    for (int j = 0; j < 2; ++j) {
      const int ch = j * 512 + tid;
      const int r = ch >> 3;
      const int wo = (ch & 7) ^ (r & 7);
      gload16(gbase + (long)r * K + wo * 8, lds + sbase + j * 4096 + wid * 512);
    }
  };

  GEMM_MAIN_LOOP(A, BT, K)

  // ---- fused epilogue ----
  const int type = n0 >> 11;            // 0=q 1=k 2=v
  const int h = (n0 & 2047) >> 7;
  const long bh = (long)((m0 >> 10) * Hn + h);
  const int s0 = m0 & 1023;

  if (type == 2) {
    // V: direct store to vStage [bh][s][128]
    unsigned short* dst = vStage + (bh * Sn + s0) * DHn;
#pragma unroll
    for (int mi = 0; mi < 4; ++mi)
#pragma unroll
      for (int ni = 0; ni < 4; ++ni)
#pragma unroll
        for (int j = 0; j < 4; ++j) {
          const int mm = wr * 64 + mi * 16 + g * 4 + j;
          const int nn = wc * 64 + ni * 16 + c;
          dst[(long)mm * DHn + nn] = f2bf(acc[mi][ni][j]);
        }
  } else {
    // q/k: drain in-flight prefetch writes, restage via LDS, rope, store wide
    asm volatile("s_waitcnt vmcnt(0)" ::: "memory");
    __syncthreads();
#pragma unroll
    for (int mi = 0; mi < 4; ++mi)
#pragma unroll
      for (int ni = 0; ni < 4; ++ni)
#pragma unroll
        for (int j = 0; j < 4; ++j) {
          const int mm = wr * 64 + mi * 16 + g * 4 + j;
          const int nn = wc * 64 + ni * 16 + c;
          lds[mm * 136 + nn] = f2bf(acc[mi][ni][j]);  // [256][136] bf16
        }
    __syncthreads();
    unsigned short* dst = (type == 0 ? qR : kR) + (bh * Sn + s0) * DHn;
    const float qsc = (type == 0) ? 0.1275174213f : 1.0f;  // log2(e)/sqrt(128)
#pragma unroll
    for (int it = 0; it < 8; ++it) {
      const int cid = it * 512 + tid;
      const int r = cid >> 4;            // 0..255 (s-local)
      const int colc = (cid & 15) * 8;   // 0..120 (d)
      union { short8 v; unsigned short u[8]; } iw, ow;
      iw.v = *reinterpret_cast<const short8*>(lds + r * 136 + colc);
      const int pos = tpos[s0 + r];
      const float4* pe = reinterpret_cast<const float4*>(rope) +
                         (long)pos * 64 + (colc >> 1);
#pragma unroll
      for (int p = 0; p < 4; ++p) {
        const float4 m2 = pe[p];
        const float xx = bf2f(iw.u[2 * p]), yy = bf2f(iw.u[2 * p + 1]);
        ow.u[2 * p]     = f2bf((m2.x * xx + m2.y * yy) * qsc);
        ow.u[2 * p + 1] = f2bf((m2.z * xx + m2.w * yy) * qsc);
      }
      *reinterpret_cast<short8*>(dst + (long)r * DHn + colc) = ow.v;
    }
  }
}

// ---------------------------------------------------------------------------
// Out-proj GEMM (f32 out), same main loop.
// ---------------------------------------------------------------------------
__global__ __launch_bounds__(512, 2) void gemm_out(
    const unsigned short* __restrict__ A, const unsigned short* __restrict__ BT,
    float* __restrict__ Cout, int N, int K) {
  __shared__ unsigned short lds[49152];
  const int tid = threadIdx.x;
  const int wid = tid >> 6, lane = tid & 63;
  const int c = lane & 15, g = lane >> 4;
  const int wr = wid >> 1, wc = wid & 1;
  const int cg7 = c & 7;

  const int nwg = gridDim.x * gridDim.y;
  const int bid = blockIdx.y * gridDim.x + blockIdx.x;
  const int swz = (bid & 7) * (nwg >> 3) + (bid >> 3);
  const int m0 = (swz % gridDim.x) * 256, n0 = (swz / gridDim.x) * 128;

  const int nt = K >> 6;
  const int tmask = nt - 1;

  float4v acc[4][4];
#pragma unroll
  for (int i = 0; i < 4; ++i)
#pragma unroll
    for (int j = 0; j < 4; ++j) acc[i][j] = (float4v){0.f, 0.f, 0.f, 0.f};
  short8 bfr[4][2];

  auto STAGE = [&](const unsigned short* gbase, int sbase) {
#pragma unroll
    for (int j = 0; j < 2; ++j) {
      const int ch = j * 512 + tid;
      const int r = ch >> 3;
      const int wo = (ch & 7) ^ (r & 7);
      gload16(gbase + (long)r * K + wo * 8, lds + sbase + j * 4096 + wid * 512);
    }
  };

  GEMM_MAIN_LOOP(A, BT, K)

#pragma unroll
  for (int mi = 0; mi < 4; ++mi)
#pragma unroll
    for (int ni = 0; ni < 4; ++ni)
#pragma unroll
      for (int j = 0; j < 4; ++j) {
        const int m = m0 + wr * 64 + mi * 16 + g * 4 + j;
        const int n = n0 + wc * 64 + ni * 16 + c;
        Cout[(long)m * N + n] = acc[mi][ni][j];
      }
}
#undef PHASE
#undef GEMM_MAIN_LOOP

// ---------------------------------------------------------------------------
// V transpose: vStage [bh][s][128] -> vT [bh][d][s]
// ---------------------------------------------------------------------------
__global__ __launch_bounds__(256) void transpose_v(
    const unsigned short* __restrict__ vStage, unsigned short* __restrict__ vT) {
  __shared__ unsigned short t[64][136];
  const int s0 = blockIdx.x * 64;
  const int h = blockIdx.y;
  const int b = blockIdx.z;
  const int tid = threadIdx.x;
  const int r = tid >> 2, cb = (tid & 3) * 32;
  const long bh = (long)(b * Hn + h);
  const unsigned short* src = vStage + (bh * Sn + s0 + r) * DHn + cb;
#pragma unroll
  for (int it = 0; it < 4; ++it)
    *reinterpret_cast<short8*>(&t[r][cb + 8 * it]) =
        *reinterpret_cast<const short8*>(src + 8 * it);
  __syncthreads();
  const int d = tid >> 1, sb = (tid & 1) * 32;
  unsigned short* dst = vT + (bh * DHn + d) * Sn + s0 + sb;
#pragma unroll
  for (int it = 0; it < 4; ++it) {
    unsigned short o[8];
#pragma unroll
    for (int e = 0; e < 8; ++e) o[e] = t[sb + 8 * it + e][d];
    *reinterpret_cast<short8*>(dst + 8 * it) = *reinterpret_cast<short8*>(&o[0]);
  }
}

// ---------------------------------------------------------------------------
// Flash attention (unchanged from R6): 4 waves/block, dbuf gload_lds K/V,
// XOR-window swizzle, exp2-domain softmax with defer-max, heavy-first order.
// ---------------------------------------------------------------------------
__global__ __launch_bounds__(256, 2) void attn_mfma(
    const unsigned short* __restrict__ qR, const unsigned short* __restrict__ kR,
    const unsigned short* __restrict__ vTd, unsigned short* __restrict__ ctx) {
  __shared__ unsigned short lds[32768];   // K dbuf @0/8192, V dbuf @16384/24576
  __shared__ unsigned short Ps[4][16][72];
  const int qt = gridDim.x - 1 - blockIdx.x;  // heavy blocks first
  const int h = blockIdx.y, b = blockIdx.z;
  const int tid = threadIdx.x, wid = tid >> 6, lane = tid & 63;
  const int c = lane & 15, g = lane >> 4, cg7 = c & 7;
  const long bh = (long)(b * Hn + h);
  const unsigned short* kbase = kR + bh * Sn * DHn;
  const unsigned short* vbase = vTd + bh * DHn * Sn;

  short8 qf[4];
  {
    const unsigned short* qrow = qR + (bh * Sn + qt * 64 + wid * 16 + c) * DHn;
#pragma unroll
    for (int kc = 0; kc < 4; ++kc)
      qf[kc] = *reinterpret_cast<const short8*>(qrow + kc * 32 + g * 8);
  }

  auto STAGE = [&](int kt, int buf) {
#pragma unroll
    for (int j = 0; j < 4; ++j) {  // K tile [64][128]
      const int ch = j * 256 + tid;
      const int r = ch >> 4, wd = ch & 15;
      const int ws = (wd & 8) | ((wd & 7) ^ (r & 7));
      gload16(kbase + (long)kt * 8192 + r * 128 + ws * 8,
              lds + buf * 8192 + j * 2048 + wid * 512);
    }
#pragma unroll
    for (int j = 0; j < 4; ++j) {  // V^T tile [128][64]
      const int ch = j * 256 + tid;
      const int d = ch >> 3, sw = ch & 7;
      gload16(vbase + (long)d * Sn + kt * 64 + ((sw ^ (d & 7)) << 3),
              lds + 16384 + buf * 8192 + j * 2048 + wid * 512);
    }
  };

  float m = -INFINITY, lsum = 0.f;
  float4v ot[8];
#pragma unroll
  for (int fd = 0; fd < 8; ++fd) ot[fd] = (float4v){0.f, 0.f, 0.f, 0.f};

  STAGE(0, 0);
  __syncthreads();
  int cur = 0;

  for (int kt = 0; kt <= qt; ++kt) {
    if (kt < qt) STAGE(kt + 1, cur ^ 1);  // prefetch flies under compute

    float4v scv[4];
#pragma unroll
    for (int f = 0; f < 4; ++f) scv[f] = (float4v){0.f, 0.f, 0.f, 0.f};
    __builtin_amdgcn_s_setprio(1);
#pragma unroll
    for (int f = 0; f < 4; ++f)
#pragma unroll
      for (int kc = 0; kc < 4; ++kc) {
        const int wp = kc * 4 + g;
        const int ws = (wp & 8) | ((wp & 7) ^ cg7);
        short8 kf = *reinterpret_cast<const short8*>(
            lds + cur * 8192 + (f * 16 + c) * 128 + ws * 8);
        scv[f] = __builtin_amdgcn_mfma_f32_16x16x32_bf16(kf, qf[kc], scv[f], 0, 0, 0);
      }
    __builtin_amdgcn_s_setprio(0);

    if (kt == qt) {
      const int qloc = wid * 16 + c;
#pragma unroll
      for (int f = 0; f < 4; ++f)
#pragma unroll
        for (int j = 0; j < 4; ++j)
          if (f * 16 + g * 4 + j > qloc) scv[f][j] = -INFINITY;
    }

    float tmax = -INFINITY;
#pragma unroll
    for (int f = 0; f < 4; ++f)
#pragma unroll
      for (int j = 0; j < 4; ++j) tmax = fmaxf(tmax, scv[f][j]);
    tmax = fmaxf(tmax, __shfl_xor(tmax, 16));
    tmax = fmaxf(tmax, __shfl_xor(tmax, 32));

    float mnew, corr;
    if (__all(tmax <= m + 8.f)) {         // defer-max: skip rescale
      mnew = m; corr = 1.f;
    } else {
      mnew = fmaxf(m, tmax);
      corr = exp2f(m - mnew);
#pragma unroll
      for (int fd = 0; fd < 8; ++fd) ot[fd] *= corr;
    }
    float psum = 0.f;
#pragma unroll
    for (int f = 0; f < 4; ++f)
#pragma unroll
      for (int j = 0; j < 4; ++j) {
        scv[f][j] = exp2f(scv[f][j] - mnew);
        psum += scv[f][j];
      }
    psum += __shfl_xor(psum, 16);
    psum += __shfl_xor(psum, 32);
    lsum = lsum * corr + psum;
    m = mnew;

#pragma unroll
    for (int f = 0; f < 4; ++f) {
      unsigned int lo = (unsigned)f2bf(scv[f][0]) | ((unsigned)f2bf(scv[f][1]) << 16);
      unsigned int hi = (unsigned)f2bf(scv[f][2]) | ((unsigned)f2bf(scv[f][3]) << 16);
      uint2 pk; pk.x = lo; pk.y = hi;
      *reinterpret_cast<uint2*>(&Ps[wid][c][f * 16 + g * 4]) = pk;
    }

    short8 pf0 = *reinterpret_cast<const short8*>(&Ps[wid][c][g * 8]);
    short8 pf1 = *reinterpret_cast<const short8*>(&Ps[wid][c][32 + g * 8]);
    __builtin_amdgcn_s_setprio(1);
#pragma unroll
    for (int fd = 0; fd < 8; ++fd) {
      short8 vf0 = *reinterpret_cast<const short8*>(
          lds + 16384 + cur * 8192 + (fd * 16 + c) * 64 + ((g ^ cg7) << 3));
      short8 vf1 = *reinterpret_cast<const short8*>(
          lds + 16384 + cur * 8192 + (fd * 16 + c) * 64 + (((g + 4) ^ cg7) << 3));
      ot[fd] = __builtin_amdgcn_mfma_f32_16x16x32_bf16(vf0, pf0, ot[fd], 0, 0, 0);
      ot[fd] = __builtin_amdgcn_mfma_f32_16x16x32_bf16(vf1, pf1, ot[fd], 0, 0, 0);
    }
    __builtin_amdgcn_s_setprio(0);

    __syncthreads();  // drains this tile's prefetch + barrier
    cur ^= 1;
  }

  const float inv = 1.0f / lsum;
  unsigned short* orow = ctx + (long)(b * Sn + qt * 64 + wid * 16 + c) * Dn + h * DHn;
#pragma unroll
  for (int fd = 0; fd < 8; ++fd) {
    const int d = fd * 16 + g * 4;
    uint2 pk;
    pk.x = (unsigned)f2bf(ot[fd][0] * inv) | ((unsigned)f2bf(ot[fd][1] * inv) << 16);
    pk.y = (unsigned)f2bf(ot[fd][2] * inv) | ((unsigned)f2bf(ot[fd][3] * inv) << 16);
    *reinterpret_cast<uint2*>(orow + d) = pk;
  }
}

// ---------------------------------------------------------------------------
extern "C" void kernel_launch(void* const* d_in, const int* in_sizes, int n_in,
                              void* d_out, int out_size, void* d_ws, size_t ws_size,
                              hipStream_t stream) {
  const float* x     = (const float*)d_in[0];
  const float* w_qkv = (const float*)d_in[1];
  const float* w_out = (const float*)d_in[2];
  const float* rope  = (const float*)d_in[3];
  const int*   tpos  = (const int*)d_in[4];
  float* out = (float*)d_out;

  unsigned short* x16    = (unsigned short*)d_ws;          // 8.4M sh
  unsigned short* wqkvT  = x16 + (size_t)BS * Dn;          // 12.6M sh
  unsigned short* woutT  = wqkvT + (size_t)Dn * QKVC;      // 4.2M sh
  unsigned short* qR     = woutT + (size_t)Dn * Dn;        // 8.4M sh (old qkv16)
  unsigned short* kR     = qR + (size_t)BS * Dn;           // 8.4M sh
  unsigned short* vStage = kR + (size_t)BS * Dn;           // 8.4M sh
  unsigned short* vT16   = vStage + (size_t)BS * Dn;       // 8.4M sh
  unsigned short* ctx16  = vT16 + (size_t)BS * Dn;         // 8.4M sh

  cvt_f32_bf16<<<(BS * Dn / 8 + 255) / 256, 256, 0, stream>>>(x, x16, BS * Dn / 8);
  {
    dim3 g1(QKVC / 64, Dn / 64);
    transpose_cvt<<<g1, 256, 0, stream>>>(w_qkv, wqkvT, Dn, QKVC);
    dim3 g2(Dn / 64, Dn / 64);
    transpose_cvt<<<g2, 256, 0, stream>>>(w_out, woutT, Dn, Dn);
  }
  {
    dim3 grid(BS / 256, QKVC / 128);  // 16 x 48 = 768
    gemm_qkv<<<grid, 512, 0, stream>>>(x16, wqkvT, rope, tpos, qR, kR, vStage, Dn);
  }
  {
    dim3 grid(Sn / 64, Hn, Bn);
    transpose_v<<<grid, 256, 0, stream>>>(vStage, vT16);
  }
  {
    dim3 grid(Sn / 64, Hn, Bn);
    attn_mfma<<<grid, 256, 0, stream>>>(qR, kR, vT16, ctx16);
  }
  {
    dim3 grid(BS / 256, Dn / 128);    // 16 x 16 = 256
    gemm_out<<<grid, 512, 0, stream>>>(ctx16, woutT, out, Dn, Dn);
  }
}

// Round 8
// 260.191 us; speedup vs baseline: 17.6303x; 1.0430x over previous
//
#include <hip/hip_runtime.h>
#include <hip/hip_bf16.h>
#include <math.h>

#define Bn 4
#define Sn 1024
#define Dn 2048
#define Hn 16
#define DHn 128
#define BS (Bn * Sn)       // 4096
#define QKVC (3 * Dn)      // 6144

typedef __attribute__((ext_vector_type(8))) short short8;   // 8 x bf16
typedef __attribute__((ext_vector_type(4))) float float4v;  // MFMA acc

// f32 -> bf16 (round-to-nearest-even)
__device__ inline unsigned short f2bf(float x) {
  union { float f; unsigned int u; } v; v.f = x;
  unsigned int r = v.u + 0x7fffu + ((v.u >> 16) & 1u);
  return (unsigned short)(r >> 16);
}
__device__ inline float bf2f(unsigned short b) {
  union { unsigned int u; float f; } v; v.u = ((unsigned int)b) << 16;
  return v.f;
}

// async global->LDS, 16B per lane. LDS dest = wave-uniform base + lane*16.
__device__ __forceinline__ void gload16(const unsigned short* g, unsigned short* l) {
  __builtin_amdgcn_global_load_lds(
      (const __attribute__((address_space(1))) unsigned int*)g,
      (__attribute__((address_space(3))) unsigned int*)l, 16, 0, 0);
}

// ---------------------------------------------------------------------------
// x f32 -> bf16, 8 elems/thread
// ---------------------------------------------------------------------------
__global__ __launch_bounds__(256) void cvt_f32_bf16(
    const float* __restrict__ in, unsigned short* __restrict__ out, int n8) {
  int id = blockIdx.x * 256 + threadIdx.x;
  if (id >= n8) return;
  const float4* p = reinterpret_cast<const float4*>(in) + 2 * (size_t)id;
  float4 a = p[0], b = p[1];
  short8 o;
  o[0] = (short)f2bf(a.x); o[1] = (short)f2bf(a.y);
  o[2] = (short)f2bf(a.z); o[3] = (short)f2bf(a.w);
  o[4] = (short)f2bf(b.x); o[5] = (short)f2bf(b.y);
  o[6] = (short)f2bf(b.z); o[7] = (short)f2bf(b.w);
  *reinterpret_cast<short8*>(out + 8 * (size_t)id) = o;
}

// ---------------------------------------------------------------------------
// Weight transpose+convert: w [K][N] f32 -> wT [N][K] bf16. 64x64 tiles.
// ---------------------------------------------------------------------------
__global__ __launch_bounds__(256) void transpose_cvt(
    const float* __restrict__ w, unsigned short* __restrict__ wT, int K, int N) {
  __shared__ unsigned short t[64][72];
  const int c0 = blockIdx.x * 64;  // N
  const int r0 = blockIdx.y * 64;  // K
  const int tid = threadIdx.x;
  const int r = tid >> 2;
  const int cb = (tid & 3) * 16;
#pragma unroll
  for (int it = 0; it < 4; ++it) {
    float4 v = *reinterpret_cast<const float4*>(&w[(long)(r0 + r) * N + c0 + cb + 4 * it]);
    t[r][cb + 4 * it + 0] = f2bf(v.x);
    t[r][cb + 4 * it + 1] = f2bf(v.y);
    t[r][cb + 4 * it + 2] = f2bf(v.z);
    t[r][cb + 4 * it + 3] = f2bf(v.w);
  }
  __syncthreads();
  unsigned short o[16];
#pragma unroll
  for (int e = 0; e < 16; ++e) o[e] = t[cb + e][r];
  unsigned short* dst = &wT[(long)(c0 + r) * K + r0 + cb];
  *reinterpret_cast<short8*>(dst) = *reinterpret_cast<short8*>(&o[0]);
  *reinterpret_cast<short8*>(dst + 8) = *reinterpret_cast<short8*>(&o[8]);
}

// ---------------------------------------------------------------------------
// Shared 256x128-tile pipelined main loop. 512 thr = 8 waves (4M x 2N),
// 64x64/wave, BK=64, LDS 96 KiB. Last K-iteration peeled: no wrap stages,
// so after the final barrier NOTHING is in flight and LDS is reusable.
// ---------------------------------------------------------------------------
#define AB8(buf, h) ((buf) * 16384 + (h) * 8192)      // shorts
#define BB8(buf) (32768 + (buf) * 8192)               // shorts

#define VMW(n)                                                                 \
  asm volatile("s_waitcnt vmcnt(" #n ")" ::: "memory");                        \
  __builtin_amdgcn_sched_barrier(0);

#define PHASE(BUF, MIH, STAGE_STMT, WAIT_STMT)                                 \
  {                                                                            \
    __builtin_amdgcn_sched_barrier(0);                                         \
    short8 afr[2][2];                                                          \
    _Pragma("unroll") for (int mi2 = 0; mi2 < 2; ++mi2) {                      \
      const int mrow = wr * 64 + ((MIH) * 2 + mi2) * 16;                       \
      const int hh = mrow >> 7;                                                \
      const int rl = (mrow & 127) + c;                                         \
      _Pragma("unroll") for (int ks = 0; ks < 2; ++ks)                         \
        afr[mi2][ks] = *(const short8*)(lds + AB8(BUF, 0) + hh * 8192 +        \
            rl * 64 + (((ks * 4 + g) ^ cg7) << 3));                            \
    }                                                                          \
    if ((MIH) == 0) {                                                          \
      _Pragma("unroll") for (int ni = 0; ni < 4; ++ni)                         \
        _Pragma("unroll") for (int ks = 0; ks < 2; ++ks)                       \
          bfr[ni][ks] = *(const short8*)(lds + BB8(BUF) +                      \
              (wc * 64 + ni * 16 + c) * 64 + (((ks * 4 + g) ^ cg7) << 3));     \
    }                                                                          \
    STAGE_STMT;                                                                \
    __builtin_amdgcn_sched_barrier(0);                                         \
    __builtin_amdgcn_s_barrier();                                              \
    asm volatile("s_waitcnt lgkmcnt(0)" ::: "memory");                         \
    __builtin_amdgcn_sched_barrier(0);                                         \
    __builtin_amdgcn_s_setprio(1);                                             \
    _Pragma("unroll") for (int mi2 = 0; mi2 < 2; ++mi2)                        \
      _Pragma("unroll") for (int ni = 0; ni < 4; ++ni)                         \
        _Pragma("unroll") for (int ks = 0; ks < 2; ++ks)                       \
          acc[(MIH) * 2 + mi2][ni] = __builtin_amdgcn_mfma_f32_16x16x32_bf16(  \
              afr[mi2][ks], bfr[ni][ks], acc[(MIH) * 2 + mi2][ni], 0, 0, 0);   \
    __builtin_amdgcn_s_setprio(0);                                             \
    WAIT_STMT                                                                  \
    __builtin_amdgcn_s_barrier();                                              \
  }

// A is staged 1 K-tile ahead within the iteration; B 1.5 tiles ahead across
// iterations. Peeled tail: stages only A(nt-1); vmcnt(0) once; zero in flight
// after the final barrier.
#define GEMM_MAIN_LOOP(A_, BT_, K_)                                            \
  STAGE(A_ + (long)m0 * K_, AB8(0, 0));                                        \
  STAGE(A_ + (long)(m0 + 128) * K_, AB8(0, 1));                                \
  STAGE(BT_ + (long)n0 * K_, BB8(0));                                          \
  STAGE(BT_ + (long)n0 * K_ + 64, BB8(1));                                     \
  VMW(2)                                                                       \
  __builtin_amdgcn_s_barrier();                                                \
  for (int it2 = 0; it2 < nt / 2 - 1; ++it2) {                                 \
    const long T1 = (long)(2 * it2 + 1) * 64;                                  \
    const long T2 = (long)(2 * it2 + 2) * 64;                                  \
    const long T3 = (long)(2 * it2 + 3) * 64;                                  \
    PHASE(0, 0, STAGE(A_ + (long)m0 * K_ + T1, AB8(1, 0)), )                   \
    PHASE(0, 1,                                                                \
          { STAGE(A_ + (long)(m0 + 128) * K_ + T1, AB8(1, 1));                 \
            STAGE(BT_ + (long)n0 * K_ + T2, BB8(0)); }, VMW(2))                \
    PHASE(1, 0, STAGE(A_ + (long)m0 * K_ + T2, AB8(0, 0)), )                   \
    PHASE(1, 1,                                                                \
          { STAGE(A_ + (long)(m0 + 128) * K_ + T2, AB8(0, 1));                 \
            STAGE(BT_ + (long)n0 * K_ + T3, BB8(1)); }, VMW(2))                \
  }                                                                            \
  {                                                                            \
    const long TL = (long)(nt - 1) * 64;                                       \
    PHASE(0, 0, STAGE(A_ + (long)m0 * K_ + TL, AB8(1, 0)), )                   \
    PHASE(0, 1, STAGE(A_ + (long)(m0 + 128) * K_ + TL, AB8(1, 1)), VMW(0))     \
    PHASE(1, 0, {}, )                                                          \
    PHASE(1, 1, {}, )                                                          \
  }

// ---------------------------------------------------------------------------
// QKV GEMM with fused rope + head-split + V-transpose epilogue.
// Tile 256x128: n-panel = exactly one head's 128 d's of q, k or v.
//   q -> qR [bh][s][128] rope'd, scaled log2(e)/sqrt(DH)
//   k -> kR [bh][s][128] rope'd
//   v -> vT [bh][d][s]   (transposed in-epilogue via LDS [128][264])
// ---------------------------------------------------------------------------
__global__ __launch_bounds__(512, 2) void gemm_qkv(
    const unsigned short* __restrict__ A, const unsigned short* __restrict__ BT,
    const float* __restrict__ rope, const int* __restrict__ tpos,
    unsigned short* __restrict__ qR, unsigned short* __restrict__ kR,
    unsigned short* __restrict__ vT, int K) {
  __shared__ unsigned short lds[49152];  // 96 KiB
  const int tid = threadIdx.x;
  const int wid = tid >> 6, lane = tid & 63;
  const int c = lane & 15, g = lane >> 4;
  const int wr = wid >> 1, wc = wid & 1;
  const int cg7 = c & 7;

  const int nwg = gridDim.x * gridDim.y;
  const int bid = blockIdx.y * gridDim.x + blockIdx.x;
  const int swz = (bid & 7) * (nwg >> 3) + (bid >> 3);
  const int m0 = (swz % gridDim.x) * 256, n0 = (swz / gridDim.x) * 128;

  const int nt = K >> 6;

  float4v acc[4][4];
#pragma unroll
  for (int i = 0; i < 4; ++i)
#pragma unroll
    for (int j = 0; j < 4; ++j) acc[i][j] = (float4v){0.f, 0.f, 0.f, 0.f};
  short8 bfr[4][2];

  auto STAGE = [&](const unsigned short* gbase, int sbase) {
#pragma unroll
    for (int j = 0; j < 2; ++j) {
      const int ch = j * 512 + tid;
      const int r = ch >> 3;
      const int wo = (ch & 7) ^ (r & 7);
      gload16(gbase + (long)r * K + wo * 8, lds + sbase + j * 4096 + wid * 512);
    }
  };

  GEMM_MAIN_LOOP(A, BT, K)

  // ---- fused epilogue (nothing in flight; LDS free after final barrier) ----
  const int type = n0 >> 11;            // 0=q 1=k 2=v
  const int h = (n0 & 2047) >> 7;
  const long bh = (long)((m0 >> 10) * Hn + h);
  const int s0 = m0 & 1023;

  if (type == 2) {
    // V: store acc TRANSPOSED into LDS [128 d][264 s-pad], then write
    // vT[bh][d][s] as 512B-contiguous coalesced segments.
#pragma unroll
    for (int mi = 0; mi < 4; ++mi)
#pragma unroll
      for (int ni = 0; ni < 4; ++ni)
#pragma unroll
        for (int j = 0; j < 4; ++j) {
          const int mm = wr * 64 + mi * 16 + g * 4 + j;   // s-local
          const int nn = wc * 64 + ni * 16 + c;           // d
          lds[nn * 264 + mm] = f2bf(acc[mi][ni][j]);
        }
    __syncthreads();
    unsigned short* dst = vT + bh * (long)DHn * Sn + s0;
#pragma unroll
    for (int it = 0; it < 8; ++it) {
      const int cid = it * 512 + tid;
      const int d = cid >> 5;            // 0..127
      const int sl = (cid & 31) * 8;     // 0..248
      short8 v = *reinterpret_cast<const short8*>(lds + d * 264 + sl);
      *reinterpret_cast<short8*>(dst + (long)d * Sn + sl) = v;
    }
  } else {
    // q/k: restage via LDS [256][136], rope pairs lane-local, store wide.
#pragma unroll
    for (int mi = 0; mi < 4; ++mi)
#pragma unroll
      for (int ni = 0; ni < 4; ++ni)
#pragma unroll
        for (int j = 0; j < 4; ++j) {
          const int mm = wr * 64 + mi * 16 + g * 4 + j;
          const int nn = wc * 64 + ni * 16 + c;
          lds[mm * 136 + nn] = f2bf(acc[mi][ni][j]);
        }
    __syncthreads();
    unsigned short* dst = (type == 0 ? qR : kR) + (bh * Sn + s0) * DHn;
    const float qsc = (type == 0) ? 0.1275174213f : 1.0f;  // log2(e)/sqrt(128)
#pragma unroll
    for (int it = 0; it < 8; ++it) {
      const int cid = it * 512 + tid;
      const int r = cid >> 4;            // 0..255 (s-local)
      const int colc = (cid & 15) * 8;   // 0..120 (d)
      union { short8 v; unsigned short u[8]; } iw, ow;
      iw.v = *reinterpret_cast<const short8*>(lds + r * 136 + colc);
      const int pos = tpos[s0 + r];
      const float4* pe = reinterpret_cast<const float4*>(rope) +
                         (long)pos * 64 + (colc >> 1);
#pragma unroll
      for (int p = 0; p < 4; ++p) {
        const float4 m2 = pe[p];
        const float xx = bf2f(iw.u[2 * p]), yy = bf2f(iw.u[2 * p + 1]);
        ow.u[2 * p]     = f2bf((m2.x * xx + m2.y * yy) * qsc);
        ow.u[2 * p + 1] = f2bf((m2.z * xx + m2.w * yy) * qsc);
      }
      *reinterpret_cast<short8*>(dst + (long)r * DHn + colc) = ow.v;
    }
  }
}

// ---------------------------------------------------------------------------
// Out-proj GEMM (f32 out), same main loop.
// ---------------------------------------------------------------------------
__global__ __launch_bounds__(512, 2) void gemm_out(
    const unsigned short* __restrict__ A, const unsigned short* __restrict__ BT,
    float* __restrict__ Cout, int N, int K) {
  __shared__ unsigned short lds[49152];
  const int tid = threadIdx.x;
  const int wid = tid >> 6, lane = tid & 63;
  const int c = lane & 15, g = lane >> 4;
  const int wr = wid >> 1, wc = wid & 1;
  const int cg7 = c & 7;

  const int nwg = gridDim.x * gridDim.y;
  const int bid = blockIdx.y * gridDim.x + blockIdx.x;
  const int swz = (bid & 7) * (nwg >> 3) + (bid >> 3);
  const int m0 = (swz % gridDim.x) * 256, n0 = (swz / gridDim.x) * 128;

  const int nt = K >> 6;

  float4v acc[4][4];
#pragma unroll
  for (int i = 0; i < 4; ++i)
#pragma unroll
    for (int j = 0; j < 4; ++j) acc[i][j] = (float4v){0.f, 0.f, 0.f, 0.f};
  short8 bfr[4][2];

  auto STAGE = [&](const unsigned short* gbase, int sbase) {
#pragma unroll
    for (int j = 0; j < 2; ++j) {
      const int ch = j * 512 + tid;
      const int r = ch >> 3;
      const int wo = (ch & 7) ^ (r & 7);
      gload16(gbase + (long)r * K + wo * 8, lds + sbase + j * 4096 + wid * 512);
    }
  };

  GEMM_MAIN_LOOP(A, BT, K)

#pragma unroll
  for (int mi = 0; mi < 4; ++mi)
#pragma unroll
    for (int ni = 0; ni < 4; ++ni)
#pragma unroll
      for (int j = 0; j < 4; ++j) {
        const int m = m0 + wr * 64 + mi * 16 + g * 4 + j;
        const int n = n0 + wc * 64 + ni * 16 + c;
        Cout[(long)m * N + n] = acc[mi][ni][j];
      }
}
#undef PHASE
#undef GEMM_MAIN_LOOP

// ---------------------------------------------------------------------------
// Flash attention (unchanged): 4 waves/block, dbuf gload_lds K/V,
// XOR-window swizzle, exp2-domain softmax with defer-max, heavy-first order.
// ---------------------------------------------------------------------------
__global__ __launch_bounds__(256, 2) void attn_mfma(
    const unsigned short* __restrict__ qR, const unsigned short* __restrict__ kR,
    const unsigned short* __restrict__ vTd, unsigned short* __restrict__ ctx) {
  __shared__ unsigned short lds[32768];   // K dbuf @0/8192, V dbuf @16384/24576
  __shared__ unsigned short Ps[4][16][72];
  const int qt = gridDim.x - 1 - blockIdx.x;  // heavy blocks first
  const int h = blockIdx.y, b = blockIdx.z;
  const int tid = threadIdx.x, wid = tid >> 6, lane = tid & 63;
  const int c = lane & 15, g = lane >> 4, cg7 = c & 7;
  const long bh = (long)(b * Hn + h);
  const unsigned short* kbase = kR + bh * Sn * DHn;
  const unsigned short* vbase = vTd + bh * DHn * Sn;

  short8 qf[4];
  {
    const unsigned short* qrow = qR + (bh * Sn + qt * 64 + wid * 16 + c) * DHn;
#pragma unroll
    for (int kc = 0; kc < 4; ++kc)
      qf[kc] = *reinterpret_cast<const short8*>(qrow + kc * 32 + g * 8);
  }

  auto STAGE = [&](int kt, int buf) {
#pragma unroll
    for (int j = 0; j < 4; ++j) {  // K tile [64][128]
      const int ch = j * 256 + tid;
      const int r = ch >> 4, wd = ch & 15;
      const int ws = (wd & 8) | ((wd & 7) ^ (r & 7));
      gload16(kbase + (long)kt * 8192 + r * 128 + ws * 8,
              lds + buf * 8192 + j * 2048 + wid * 512);
    }
#pragma unroll
    for (int j = 0; j < 4; ++j) {  // V^T tile [128][64]
      const int ch = j * 256 + tid;
      const int d = ch >> 3, sw = ch & 7;
      gload16(vbase + (long)d * Sn + kt * 64 + ((sw ^ (d & 7)) << 3),
              lds + 16384 + buf * 8192 + j * 2048 + wid * 512);
    }
  };

  float m = -INFINITY, lsum = 0.f;
  float4v ot[8];
#pragma unroll
  for (int fd = 0; fd < 8; ++fd) ot[fd] = (float4v){0.f, 0.f, 0.f, 0.f};

  STAGE(0, 0);
  __syncthreads();
  int cur = 0;

  for (int kt = 0; kt <= qt; ++kt) {
    if (kt < qt) STAGE(kt + 1, cur ^ 1);  // prefetch flies under compute

    float4v scv[4];
#pragma unroll
    for (int f = 0; f < 4; ++f) scv[f] = (float4v){0.f, 0.f, 0.f, 0.f};
    __builtin_amdgcn_s_setprio(1);
#pragma unroll
    for (int f = 0; f < 4; ++f)
#pragma unroll
      for (int kc = 0; kc < 4; ++kc) {
        const int wp = kc * 4 + g;
        const int ws = (wp & 8) | ((wp & 7) ^ cg7);
        short8 kf = *reinterpret_cast<const short8*>(
            lds + cur * 8192 + (f * 16 + c) * 128 + ws * 8);
        scv[f] = __builtin_amdgcn_mfma_f32_16x16x32_bf16(kf, qf[kc], scv[f], 0, 0, 0);
      }
    __builtin_amdgcn_s_setprio(0);

    if (kt == qt) {
      const int qloc = wid * 16 + c;
#pragma unroll
      for (int f = 0; f < 4; ++f)
#pragma unroll
        for (int j = 0; j < 4; ++j)
          if (f * 16 + g * 4 + j > qloc) scv[f][j] = -INFINITY;
    }

    float tmax = -INFINITY;
#pragma unroll
    for (int f = 0; f < 4; ++f)
#pragma unroll
      for (int j = 0; j < 4; ++j) tmax = fmaxf(tmax, scv[f][j]);
    tmax = fmaxf(tmax, __shfl_xor(tmax, 16));
    tmax = fmaxf(tmax, __shfl_xor(tmax, 32));

    float mnew, corr;
    if (__all(tmax <= m + 8.f)) {         // defer-max: skip rescale
      mnew = m; corr = 1.f;
    } else {
      mnew = fmaxf(m, tmax);
      corr = exp2f(m - mnew);
#pragma unroll
      for (int fd = 0; fd < 8; ++fd) ot[fd] *= corr;
    }
    float psum = 0.f;
#pragma unroll
    for (int f = 0; f < 4; ++f)
#pragma unroll
      for (int j = 0; j < 4; ++j) {
        scv[f][j] = exp2f(scv[f][j] - mnew);
        psum += scv[f][j];
      }
    psum += __shfl_xor(psum, 16);
    psum += __shfl_xor(psum, 32);
    lsum = lsum * corr + psum;
    m = mnew;

#pragma unroll
    for (int f = 0; f < 4; ++f) {
      unsigned int lo = (unsigned)f2bf(scv[f][0]) | ((unsigned)f2bf(scv[f][1]) << 16);
      unsigned int hi = (unsigned)f2bf(scv[f][2]) | ((unsigned)f2bf(scv[f][3]) << 16);
      uint2 pk; pk.x = lo; pk.y = hi;
      *reinterpret_cast<uint2*>(&Ps[wid][c][f * 16 + g * 4]) = pk;
    }

    short8 pf0 = *reinterpret_cast<const short8*>(&Ps[wid][c][g * 8]);
    short8 pf1 = *reinterpret_cast<const short8*>(&Ps[wid][c][32 + g * 8]);
    __builtin_amdgcn_s_setprio(1);
#pragma unroll
    for (int fd = 0; fd < 8; ++fd) {
      short8 vf0 = *reinterpret_cast<const short8*>(
          lds + 16384 + cur * 8192 + (fd * 16 + c) * 64 + ((g ^ cg7) << 3));
      short8 vf1 = *reinterpret_cast<const short8*>(
          lds + 16384 + cur * 8192 + (fd * 16 + c) * 64 + (((g + 4) ^ cg7) << 3));
      ot[fd] = __builtin_amdgcn_mfma_f32_16x16x32_bf16(vf0, pf0, ot[fd], 0, 0, 0);
      ot[fd] = __builtin_amdgcn_mfma_f32_16x16x32_bf16(vf1, pf1, ot[fd], 0, 0, 0);
    }
    __builtin_amdgcn_s_setprio(0);

    __syncthreads();  // drains this tile's prefetch + barrier
    cur ^= 1;
  }

  const float inv = 1.0f / lsum;
  unsigned short* orow = ctx + (long)(b * Sn + qt * 64 + wid * 16 + c) * Dn + h * DHn;
#pragma unroll
  for (int fd = 0; fd < 8; ++fd) {
    const int d = fd * 16 + g * 4;
    uint2 pk;
    pk.x = (unsigned)f2bf(ot[fd][0] * inv) | ((unsigned)f2bf(ot[fd][1] * inv) << 16);
    pk.y = (unsigned)f2bf(ot[fd][2] * inv) | ((unsigned)f2bf(ot[fd][3] * inv) << 16);
    *reinterpret_cast<uint2*>(orow + d) = pk;
  }
}

// ---------------------------------------------------------------------------
extern "C" void kernel_launch(void* const* d_in, const int* in_sizes, int n_in,
                              void* d_out, int out_size, void* d_ws, size_t ws_size,
                              hipStream_t stream) {
  const float* x     = (const float*)d_in[0];
  const float* w_qkv = (const float*)d_in[1];
  const float* w_out = (const float*)d_in[2];
  const float* rope  = (const float*)d_in[3];
  const int*   tpos  = (const int*)d_in[4];
  float* out = (float*)d_out;

  unsigned short* x16    = (unsigned short*)d_ws;          // 8.4M sh
  unsigned short* wqkvT  = x16 + (size_t)BS * Dn;          // 12.6M sh
  unsigned short* woutT  = wqkvT + (size_t)Dn * QKVC;      // 4.2M sh
  unsigned short* qR     = woutT + (size_t)Dn * Dn;        // 8.4M sh
  unsigned short* kR     = qR + (size_t)BS * Dn;           // 8.4M sh
  unsigned short* vT16   = kR + (size_t)BS * Dn;           // 8.4M sh
  unsigned short* ctx16  = vT16 + (size_t)BS * Dn;         // 8.4M sh

  cvt_f32_bf16<<<(BS * Dn / 8 + 255) / 256, 256, 0, stream>>>(x, x16, BS * Dn / 8);
  {
    dim3 g1(QKVC / 64, Dn / 64);
    transpose_cvt<<<g1, 256, 0, stream>>>(w_qkv, wqkvT, Dn, QKVC);
    dim3 g2(Dn / 64, Dn / 64);
    transpose_cvt<<<g2, 256, 0, stream>>>(w_out, woutT, Dn, Dn);
  }
  {
    dim3 grid(BS / 256, QKVC / 128);  // 16 x 48 = 768
    gemm_qkv<<<grid, 512, 0, stream>>>(x16, wqkvT, rope, tpos, qR, kR, vT16, Dn);
  }
  {
    dim3 grid(Sn / 64, Hn, Bn);
    attn_mfma<<<grid, 256, 0, stream>>>(qR, kR, vT16, ctx16);
  }
  {
    dim3 grid(BS / 256, Dn / 128);    // 16 x 16 = 256
    gemm_out<<<grid, 512, 0, stream>>>(ctx16, woutT, out, Dn, Dn);
  }
}